// Round 3
// baseline (309.670 us; speedup 1.0000x reference)
//
#include <hip/hip_runtime.h>
#include <math.h>

#define ROWS 18496          // bt*J*N = 64*17*17
#define SCALE 0.17677669529663687f  // 1/sqrt(32)

typedef unsigned short ushort_t;
typedef __attribute__((ext_vector_type(8))) short short8;
typedef __attribute__((ext_vector_type(4))) float f32x4;

__device__ __forceinline__ void fma4(float4& d, float s, const float4& v) {
    d.x = fmaf(s, v.x, d.x); d.y = fmaf(s, v.y, d.y);
    d.z = fmaf(s, v.z, d.z); d.w = fmaf(s, v.w, d.w);
}
__device__ __forceinline__ float dot4(const float4& a, const float4& b) {
    return a.x*b.x + a.y*b.y + a.z*b.z + a.w*b.w;
}

__device__ __forceinline__ ushort_t f2bf(float x) {
    union { float f; unsigned u; } v; v.f = x;
    unsigned r = v.u + 0x7fffu + ((v.u >> 16) & 1u);
    return (ushort_t)(r >> 16);
}
__device__ __forceinline__ float bf2f(ushort_t b) {
    union { unsigned u; float f; } v; v.u = ((unsigned)b) << 16; return v.f;
}

__device__ __forceinline__ void gl_lds16(const void* g, void* l) {
    __builtin_amdgcn_global_load_lds(
        (const __attribute__((address_space(1))) void*)g,
        (__attribute__((address_space(3))) void*)l, 16, 0, 0);
}

__device__ __forceinline__ void store_hilo(ushort_t* yhi, ushort_t* ylo,
                                           size_t off, const float4& a)
{
    ushort4 h, l;
    h.x = f2bf(a.x); l.x = f2bf(a.x - bf2f(h.x));
    h.y = f2bf(a.y); l.y = f2bf(a.y - bf2f(h.y));
    h.z = f2bf(a.z); l.z = f2bf(a.z - bf2f(h.z));
    h.w = f2bf(a.w); l.w = f2bf(a.w - bf2f(h.w));
    *(ushort4*)&yhi[off] = h;
    *(ushort4*)&ylo[off] = l;
}

// ---------------- merged conversion kernel ----------------------------
__global__ __launch_bounds__(256) void k_cvt_xw(
    const float4* __restrict__ x, ushort4* __restrict__ xhi, ushort4* __restrict__ xlo,
    const float* __restrict__ W, ushort_t* __restrict__ bh, ushort_t* __restrict__ bl)
{
    if (blockIdx.x < 4624) {
        int i = blockIdx.x * 256 + threadIdx.x;
        float4 v = x[i];
        ushort4 h, l;
        h.x = f2bf(v.x); l.x = f2bf(v.x - bf2f(h.x));
        h.y = f2bf(v.y); l.y = f2bf(v.y - bf2f(h.y));
        h.z = f2bf(v.z); l.z = f2bf(v.z - bf2f(h.z));
        h.w = f2bf(v.w); l.w = f2bf(v.w - bf2f(h.w));
        xhi[i] = h; xlo[i] = l;
    } else {
        int o = blockIdx.x - 4624;   // 0..1279
        int kk = threadIdx.x;        // 0..255
        int col = (o & 255) * 5 + (o >> 8);
        float v = W[(size_t)kk * 1280 + col];
        ushort_t hh = f2bf(v);
        bh[(size_t)o * 256 + kk] = hh;
        bl[(size_t)o * 256 + kk] = f2bf(v - bf2f(hh));
    }
}

// Wp (768x256 f32) -> transposed bf16 [n][k]
__global__ __launch_bounds__(256) void k_cvt_wp(
    const float* __restrict__ W, ushort_t* __restrict__ bh, ushort_t* __restrict__ bl)
{
    int n = blockIdx.x;          // 0..255
    for (int k = threadIdx.x; k < 768; k += 256) {
        float v = W[(size_t)k * 256 + n];
        ushort_t h = f2bf(v);
        bh[(size_t)n * 768 + k] = h;
        bl[(size_t)n * 768 + k] = f2bf(v - bf2f(h));
    }
}

// ---------------- split-bf16 MFMA GEMM --------------------------------
template<int BM, int BN, int K, int MODE>
__global__ __launch_bounds__(256) void k_gemm(
    const ushort_t* __restrict__ Ahi, const ushort_t* __restrict__ Alo,
    const ushort_t* __restrict__ Bhi, const ushort_t* __restrict__ Blo,
    const float* __restrict__ aux,
    float* __restrict__ out)
{
    constexpr int MT = BM / 32;
    constexpr int NT = BN / 32;
    __shared__ __attribute__((aligned(16))) ushort_t sAh[BM * 32];
    __shared__ __attribute__((aligned(16))) ushort_t sAl[BM * 32];
    __shared__ __attribute__((aligned(16))) ushort_t sBh[BN * 32];
    __shared__ __attribute__((aligned(16))) ushort_t sBl[BN * 32];

    const int t = threadIdx.x;
    const int lane = t & 63;
    const int ln = lane & 15, quad = lane >> 4;
    const int wave = t >> 6;
    const int wm = wave >> 1, wn = wave & 1;
    const int m0 = blockIdx.y * BM, n0 = blockIdx.x * BN;

    f32x4 acc[MT][NT];
#pragma unroll
    for (int i = 0; i < MT; ++i)
#pragma unroll
        for (int j = 0; j < NT; ++j) acc[i][j] = (f32x4){0.f, 0.f, 0.f, 0.f};

    for (int kb = 0; kb < K; kb += 32) {
        __syncthreads();
#pragma unroll
        for (int s = t; s < BM * 4; s += 256) {
            int row = s >> 2, kc = s & 3;
            int gr = m0 + row; if (gr > ROWS - 1) gr = ROWS - 1;
            size_t gb = ((size_t)gr * K + kb) * 2 + kc * 16;
            int lb = (s & ~63) * 16;
            gl_lds16((const char*)Ahi + gb, (char*)sAh + lb);
            gl_lds16((const char*)Alo + gb, (char*)sAl + lb);
        }
#pragma unroll
        for (int s = t; s < BN * 4; s += 256) {
            int row = s >> 2, kc = s & 3;
            size_t gb = ((size_t)(n0 + row) * K + kb) * 2 + kc * 16;
            int lb = (s & ~63) * 16;
            gl_lds16((const char*)Bhi + gb, (char*)sBh + lb);
            gl_lds16((const char*)Blo + gb, (char*)sBl + lb);
        }
        __syncthreads();

        short8 ah[MT], al[MT], bh[NT], bl[NT];
#pragma unroll
        for (int i = 0; i < MT; ++i) {
            int off = (wm * (BM / 2) + i * 16 + ln) * 32 + quad * 8;
            ah[i] = *(const short8*)&sAh[off];
            al[i] = *(const short8*)&sAl[off];
        }
#pragma unroll
        for (int j = 0; j < NT; ++j) {
            int off = (wn * (BN / 2) + j * 16 + ln) * 32 + quad * 8;
            bh[j] = *(const short8*)&sBh[off];
            bl[j] = *(const short8*)&sBl[off];
        }
#pragma unroll
        for (int i = 0; i < MT; ++i)
#pragma unroll
            for (int j = 0; j < NT; ++j) {
                acc[i][j] = __builtin_amdgcn_mfma_f32_16x16x32_bf16(ah[i], bh[j], acc[i][j], 0, 0, 0);
                acc[i][j] = __builtin_amdgcn_mfma_f32_16x16x32_bf16(ah[i], bl[j], acc[i][j], 0, 0, 0);
                acc[i][j] = __builtin_amdgcn_mfma_f32_16x16x32_bf16(al[i], bh[j], acc[i][j], 0, 0, 0);
            }
    }

#pragma unroll
    for (int i = 0; i < MT; ++i) {
#pragma unroll
        for (int r = 0; r < 4; ++r) {
            int gm = m0 + wm * (BM / 2) + i * 16 + quad * 4 + r;
            if (gm >= ROWS) continue;
            if (MODE == 0) {
                int jn = gm % 289;
                const float* Mrow = &aux[(size_t)jn * 256];
#pragma unroll
                for (int j = 0; j < NT; ++j) {
                    int gn = n0 + wn * (BN / 2) + j * 16 + ln;
                    out[(size_t)gm * 1280 + gn] = acc[i][j][r] * Mrow[gn & 255];
                }
            } else {
#pragma unroll
                for (int j = 0; j < NT; ++j) {
                    int gn = n0 + wn * (BN / 2) + j * 16 + ln;
                    out[(size_t)gm * 256 + gn] = acc[i][j][r] + aux[gn];
                }
            }
        }
    }
}

// ---------------- fused attention: scores + softmaxes + all combines -----
// 512 threads (8 waves) per (b,h), grid 512. LDS 63.5 KB -> 2 blocks/CU.
// Register discipline (round-2 lesson: VGPR=120 blocked the 2nd block/CU,
// occupancy 21% vs round-1's 44% at VGPR=64):
//  - P1 keeps NO accumulators live across the ch staging loop: each ch pass
//    computes tmp[17] and accumulates into aS/aV in LDS (ch0 writes, ch1
//    RMW-adds; same thread owns the row in both passes -> no race).
//  - P3 is 1 point/unit (1156 uniform units); unit state dies in-loop.
//  - __launch_bounds__(512, 2): on this toolchain the 2nd arg behaves as
//    CUDA minBlocksPerCU (round-1: arg 4 -> 64 VGPRs = 2048/32 waves), so
//    2 -> cap 128 VGPRs and request 2 blocks/CU.
__global__ __launch_bounds__(512, 2) void k_att(
    const float* __restrict__ qkv5,
    const float* __restrict__ A_s, const float* __restrict__ A_v,
    const float* __restrict__ adjS, const float* __restrict__ adjV,
    ushort_t* __restrict__ yhi, ushort_t* __restrict__ ylo)
{
    __shared__ __attribute__((aligned(16))) float sm[16184];
    float* aS  = sm;            // 4913  [n][j][k]
    float* aV  = sm + 4913;     // 4913  [j][n][m]
    float* ebS = sm + 9826;     // 289
    float* ebV = sm + 10115;    // 289
    float* buf = sm + 10404;    // 289*20

    const int t  = threadIdx.x;
    const int bh = blockIdx.x;
    const int b  = bh >> 3, h = bh & 7;
    const size_t rowbase = (size_t)b * 289;

    // ---- P0: exp of symmetrized biases ----
    for (int idx = t; idx < 578; idx += 512) {
        int f = idx / 289, rem = idx % 289;
        int jj = rem / 17, kk = rem % 17;
        float bias;
        if (f == 0)
            bias = 0.5f * ((A_s[jj*17+kk] + adjS[jj*17+kk]) + (A_s[kk*17+jj] + adjS[kk*17+jj]));
        else
            bias = 0.5f * ((A_v[jj*17+kk] + adjV[jj*17+kk]) + (A_v[kk*17+jj] + adjV[kk*17+jj]));
        (f ? ebV : ebS)[rem] = expf(bias);
    }

    // ---- P1: raw scores, LDS-accumulated across the 2 ch passes ----
    // unit u < 289: S-scores for q-row u -> aS[n][j][.]
    // unit u >=289: V-scores for q-row u-289 -> aV[j][n][.]
    for (int ch = 0; ch < 2; ++ch) {
        __syncthreads();
        for (int idx = t; idx < 1156; idx += 512) {
            int p = idx >> 2, c = idx & 3;
            *(float4*)&buf[p * 20 + c * 4] =
                *(const float4*)&qkv5[(rowbase + p) * 1280 + 256 + h * 32 + ch * 16 + c * 4];
        }
        __syncthreads();
        for (int u = t; u < 578; u += 512) {
            const bool isS = (u < 289);
            const int p = isS ? u : u - 289;
            const float* qp = &qkv5[(rowbase + p) * 1280 + h * 32 + ch * 16];
            float4 q0 = *(const float4*)&qp[0];
            float4 q1 = *(const float4*)&qp[4];
            float4 q2 = *(const float4*)&qp[8];
            float4 q3 = *(const float4*)&qp[12];
            const int a = p / 17, bb = p % 17;
            float tmp[17];
            if (isS) {
#pragma unroll
                for (int kk = 0; kk < 17; ++kk) {
                    const float4* r = (const float4*)&buf[(kk * 17 + bb) * 20];
                    tmp[kk] = dot4(q0, r[0]) + dot4(q1, r[1]) + dot4(q2, r[2]) + dot4(q3, r[3]);
                }
                float* dst = &aS[bb * 289 + a * 17];
                if (ch == 0) {
#pragma unroll
                    for (int kk = 0; kk < 17; ++kk) dst[kk] = tmp[kk];
                } else {
#pragma unroll
                    for (int kk = 0; kk < 17; ++kk) dst[kk] += tmp[kk];
                }
            } else {
#pragma unroll
                for (int mm = 0; mm < 17; ++mm) {
                    const float4* r = (const float4*)&buf[(a * 17 + mm) * 20];
                    tmp[mm] = dot4(q0, r[0]) + dot4(q1, r[1]) + dot4(q2, r[2]) + dot4(q3, r[3]);
                }
                float* dst = &aV[a * 289 + bb * 17];
                if (ch == 0) {
#pragma unroll
                    for (int mm = 0; mm < 17; ++mm) dst[mm] = tmp[mm];
                } else {
#pragma unroll
                    for (int mm = 0; mm < 17; ++mm) dst[mm] += tmp[mm];
                }
            }
        }
    }
    __syncthreads();

    // ---- P2: in-place softmax on all 578 rows (SCALE folded in) ----
    for (int idx = t; idx < 578; idx += 512) {
        float* row = (idx < 289) ? &aS[idx * 17] : &aV[(idx - 289) * 17];
        float v[17];
#pragma unroll
        for (int kk = 0; kk < 17; ++kk) v[kk] = row[kk] * SCALE;
        float mx = v[0];
#pragma unroll
        for (int kk = 1; kk < 17; ++kk) mx = fmaxf(mx, v[kk]);
        float sum = 0.f;
#pragma unroll
        for (int kk = 0; kk < 17; ++kk) { v[kk] = expf(v[kk] - mx); sum += v[kk]; }
        float inv = 1.f / sum;
#pragma unroll
        for (int kk = 0; kk < 17; ++kk) row[kk] = v[kk] * inv;
    }
    // (no sync needed: P3's staging sync orders P2 before consumers)

    // ---- P3: x_vsv -> y cols 0..255. 1156 uniform units (1 point x c4) ----
    for (int ch = 0; ch < 2; ++ch) {
        __syncthreads();
        for (int idx = t; idx < 1156; idx += 512) {
            int p = idx >> 2, c = idx & 3;
            *(float4*)&buf[p * 20 + c * 4] =
                *(const float4*)&qkv5[(rowbase + p) * 1280 + 1024 + h * 32 + ch * 16 + c * 4];
        }
        __syncthreads();
        for (int u = t; u < 1156; u += 512) {
            const int c4 = (u & 3) * 4;
            const int p = u >> 2;                 // 0..288
            const int jj = p / 17, nn = p % 17;
            float eV[17];
            {
                const float* s0 = &aV[jj * 289 + nn * 17];
#pragma unroll
                for (int m = 0; m < 17; ++m) eV[m] = s0[m];
            }
            float4 acc0 = {0,0,0,0};
            for (int kk = 0; kk < 17; ++kk) {
                float4 tg0 = {0,0,0,0};
#pragma unroll
                for (int m = 0; m < 17; ++m) {
                    float4 v = *(const float4*)&buf[(kk * 17 + m) * 20 + c4];
                    fma4(tg0, eV[m], v);
                }
                fma4(acc0, aS[nn * 289 + jj * 17 + kk], tg0);
            }
            store_hilo(yhi, ylo, (rowbase + p) * 768 + h * 32 + ch * 16 + c4, acc0);
        }
    }

    // ---- P4: x_vs (aS2 = normalize(aS*ebS)) -> y cols 256..511 ----------
    for (int ch = 0; ch < 2; ++ch) {
        __syncthreads();
        for (int idx = t; idx < 1156; idx += 512) {
            int p = idx >> 2, c = idx & 3;
            *(float4*)&buf[p * 20 + c * 4] =
                *(const float4*)&qkv5[(rowbase + p) * 1280 + 512 + h * 32 + ch * 16 + c * 4];
        }
        __syncthreads();
        for (int u = t; u < 1156; u += 512) {
            const int c4 = (u & 3) * 4, rest = u >> 2;   // rest 0..288
            const int n = rest % 17, j = rest / 17;
            float w[17];
            float s = 0.f;
            const float* as = &aS[n * 289 + j * 17];
            const float* eb = &ebS[j * 17];
#pragma unroll
            for (int kk = 0; kk < 17; ++kk) { w[kk] = as[kk] * eb[kk]; s += w[kk]; }
            const float inv = 1.f / s;
            float4 a0 = {0,0,0,0};
            for (int kk = 0; kk < 17; ++kk) {
                float4 v = *(const float4*)&buf[(kk * 17 + n) * 20 + c4];
                fma4(a0, w[kk], v);
            }
            a0.x *= inv; a0.y *= inv; a0.z *= inv; a0.w *= inv;
            store_hilo(yhi, ylo, (rowbase + j * 17 + n) * 768 + 256 + h * 32 + ch * 16 + c4, a0);
        }
    }

    // ---- P5: x_vv (aV2 = normalize(aV*ebV)) -> y cols 512..767 ----------
    for (int ch = 0; ch < 2; ++ch) {
        __syncthreads();
        for (int idx = t; idx < 1156; idx += 512) {
            int p = idx >> 2, c = idx & 3;
            *(float4*)&buf[p * 20 + c * 4] =
                *(const float4*)&qkv5[(rowbase + p) * 1280 + 768 + h * 32 + ch * 16 + c * 4];
        }
        __syncthreads();
        for (int u = t; u < 1156; u += 512) {
            const int c4 = (u & 3) * 4, rest = u >> 2;   // rest 0..288
            const int j = rest % 17, n = rest / 17;
            float w[17];
            float s = 0.f;
            const float* av = &aV[j * 289 + n * 17];
            const float* eb = &ebV[n * 17];
#pragma unroll
            for (int mm = 0; mm < 17; ++mm) { w[mm] = av[mm] * eb[mm]; s += w[mm]; }
            const float inv = 1.f / s;
            float4 a0 = {0,0,0,0};
            for (int mm = 0; mm < 17; ++mm) {
                float4 v = *(const float4*)&buf[(j * 17 + mm) * 20 + c4];
                fma4(a0, w[mm], v);
            }
            a0.x *= inv; a0.y *= inv; a0.z *= inv; a0.w *= inv;
            store_hilo(yhi, ylo, (rowbase + j * 17 + n) * 768 + 512 + h * 32 + ch * 16 + c4, a0);
        }
    }
}

extern "C" void kernel_launch(void* const* d_in, const int* in_sizes, int n_in,
                              void* d_out, int out_size, void* d_ws, size_t ws_size,
                              hipStream_t stream)
{
    const float* x    = (const float*)d_in[0];
    const float* A_s  = (const float*)d_in[1];
    const float* A_v  = (const float*)d_in[2];
    const float* Wqkv = (const float*)d_in[3];
    const float* Wp   = (const float*)d_in[4];
    const float* bp   = (const float*)d_in[5];
    const float* M    = (const float*)d_in[6];
    const float* adjS = (const float*)d_in[7];
    const float* adjV = (const float*)d_in[8];
    float* out = (float*)d_out;

    char* w = (char*)d_ws;
    float*    qkv5  = (float*)w;                          // 95 MB, dead after k_att
    ushort_t* wph   = (ushort_t*)w;                       // written after k_att
    ushort_t* wpl   = (ushort_t*)(w + 393216);
    char* R = w + 134946816;
    ushort_t* xhi = (ushort_t*)R;
    ushort_t* xlo = (ushort_t*)(R + 9469952);
    ushort_t* wqh = (ushort_t*)(R + 18939904);
    ushort_t* wql = (ushort_t*)(R + 19595264);
    ushort_t* yhi = (ushort_t*)R;                         // alias (after qkv gemm done)
    ushort_t* ylo = (ushort_t*)(R + 28422144);

    k_cvt_xw<<<dim3(5904), 256, 0, stream>>>((const float4*)x, (ushort4*)xhi, (ushort4*)xlo,
                                             Wqkv, wqh, wql);
    k_gemm<128, 128, 256, 0><<<dim3(10, 145), 256, 0, stream>>>(xhi, xlo, wqh, wql, M, qkv5);
    k_att<<<dim3(512), 512, 0, stream>>>(qkv5, A_s, A_v, adjS, adjV, yhi, ylo);
    k_cvt_wp<<<dim3(256), 256, 0, stream>>>(Wp, wph, wpl);
    k_gemm<128, 64, 768, 1><<<dim3(4, 145), 256, 0, stream>>>(yhi, ylo, wph, wpl, bp, out);
}

// Round 5
// 297.540 us; speedup vs baseline: 1.0408x; 1.0408x over previous
//
#include <hip/hip_runtime.h>
#include <math.h>

#define ROWS 18496          // bt*J*N = 64*17*17
#define SCALE 0.17677669529663687f  // 1/sqrt(32)

typedef unsigned short ushort_t;
typedef __attribute__((ext_vector_type(8))) short short8;
typedef __attribute__((ext_vector_type(4))) float f32x4;

__device__ __forceinline__ void fma4(float4& d, float s, const float4& v) {
    d.x = fmaf(s, v.x, d.x); d.y = fmaf(s, v.y, d.y);
    d.z = fmaf(s, v.z, d.z); d.w = fmaf(s, v.w, d.w);
}
__device__ __forceinline__ float dot4(const float4& a, const float4& b) {
    return a.x*b.x + a.y*b.y + a.z*b.z + a.w*b.w;
}

__device__ __forceinline__ ushort_t f2bf(float x) {
    union { float f; unsigned u; } v; v.f = x;
    unsigned r = v.u + 0x7fffu + ((v.u >> 16) & 1u);
    return (ushort_t)(r >> 16);
}
__device__ __forceinline__ float bf2f(ushort_t b) {
    union { unsigned u; float f; } v; v.u = ((unsigned)b) << 16; return v.f;
}

__device__ __forceinline__ void gl_lds16(const void* g, void* l) {
    __builtin_amdgcn_global_load_lds(
        (const __attribute__((address_space(1))) void*)g,
        (__attribute__((address_space(3))) void*)l, 16, 0, 0);
}

__device__ __forceinline__ void store_hilo(ushort_t* yhi, ushort_t* ylo,
                                           size_t off, const float4& a)
{
    ushort4 h, l;
    h.x = f2bf(a.x); l.x = f2bf(a.x - bf2f(h.x));
    h.y = f2bf(a.y); l.y = f2bf(a.y - bf2f(h.y));
    h.z = f2bf(a.z); l.z = f2bf(a.z - bf2f(h.z));
    h.w = f2bf(a.w); l.w = f2bf(a.w - bf2f(h.w));
    *(ushort4*)&yhi[off] = h;
    *(ushort4*)&ylo[off] = l;
}

// ---------------- merged conversion kernel ----------------------------
__global__ __launch_bounds__(256) void k_cvt_xw(
    const float4* __restrict__ x, ushort4* __restrict__ xhi, ushort4* __restrict__ xlo,
    const float* __restrict__ W, ushort_t* __restrict__ bh, ushort_t* __restrict__ bl)
{
    if (blockIdx.x < 4624) {
        int i = blockIdx.x * 256 + threadIdx.x;
        float4 v = x[i];
        ushort4 h, l;
        h.x = f2bf(v.x); l.x = f2bf(v.x - bf2f(h.x));
        h.y = f2bf(v.y); l.y = f2bf(v.y - bf2f(h.y));
        h.z = f2bf(v.z); l.z = f2bf(v.z - bf2f(h.z));
        h.w = f2bf(v.w); l.w = f2bf(v.w - bf2f(h.w));
        xhi[i] = h; xlo[i] = l;
    } else {
        int o = blockIdx.x - 4624;   // 0..1279
        int kk = threadIdx.x;        // 0..255
        int col = (o & 255) * 5 + (o >> 8);
        float v = W[(size_t)kk * 1280 + col];
        ushort_t hh = f2bf(v);
        bh[(size_t)o * 256 + kk] = hh;
        bl[(size_t)o * 256 + kk] = f2bf(v - bf2f(hh));
    }
}

// Wp (768x256 f32) -> transposed bf16 [n][k]
__global__ __launch_bounds__(256) void k_cvt_wp(
    const float* __restrict__ W, ushort_t* __restrict__ bh, ushort_t* __restrict__ bl)
{
    int n = blockIdx.x;          // 0..255
    for (int k = threadIdx.x; k < 768; k += 256) {
        float v = W[(size_t)k * 256 + n];
        ushort_t h = f2bf(v);
        bh[(size_t)n * 768 + k] = h;
        bl[(size_t)n * 768 + k] = f2bf(v - bf2f(h));
    }
}

// ---------------- split-bf16 MFMA GEMM --------------------------------
template<int BM, int BN, int K, int MODE>
__global__ __launch_bounds__(256) void k_gemm(
    const ushort_t* __restrict__ Ahi, const ushort_t* __restrict__ Alo,
    const ushort_t* __restrict__ Bhi, const ushort_t* __restrict__ Blo,
    const float* __restrict__ aux,
    float* __restrict__ out)
{
    constexpr int MT = BM / 32;
    constexpr int NT = BN / 32;
    __shared__ __attribute__((aligned(16))) ushort_t sAh[BM * 32];
    __shared__ __attribute__((aligned(16))) ushort_t sAl[BM * 32];
    __shared__ __attribute__((aligned(16))) ushort_t sBh[BN * 32];
    __shared__ __attribute__((aligned(16))) ushort_t sBl[BN * 32];

    const int t = threadIdx.x;
    const int lane = t & 63;
    const int ln = lane & 15, quad = lane >> 4;
    const int wave = t >> 6;
    const int wm = wave >> 1, wn = wave & 1;
    const int m0 = blockIdx.y * BM, n0 = blockIdx.x * BN;

    f32x4 acc[MT][NT];
#pragma unroll
    for (int i = 0; i < MT; ++i)
#pragma unroll
        for (int j = 0; j < NT; ++j) acc[i][j] = (f32x4){0.f, 0.f, 0.f, 0.f};

    for (int kb = 0; kb < K; kb += 32) {
        __syncthreads();
#pragma unroll
        for (int s = t; s < BM * 4; s += 256) {
            int row = s >> 2, kc = s & 3;
            int gr = m0 + row; if (gr > ROWS - 1) gr = ROWS - 1;
            size_t gb = ((size_t)gr * K + kb) * 2 + kc * 16;
            int lb = (s & ~63) * 16;
            gl_lds16((const char*)Ahi + gb, (char*)sAh + lb);
            gl_lds16((const char*)Alo + gb, (char*)sAl + lb);
        }
#pragma unroll
        for (int s = t; s < BN * 4; s += 256) {
            int row = s >> 2, kc = s & 3;
            size_t gb = ((size_t)(n0 + row) * K + kb) * 2 + kc * 16;
            int lb = (s & ~63) * 16;
            gl_lds16((const char*)Bhi + gb, (char*)sBh + lb);
            gl_lds16((const char*)Blo + gb, (char*)sBl + lb);
        }
        __syncthreads();

        short8 ah[MT], al[MT], bh[NT], bl[NT];
#pragma unroll
        for (int i = 0; i < MT; ++i) {
            int off = (wm * (BM / 2) + i * 16 + ln) * 32 + quad * 8;
            ah[i] = *(const short8*)&sAh[off];
            al[i] = *(const short8*)&sAl[off];
        }
#pragma unroll
        for (int j = 0; j < NT; ++j) {
            int off = (wn * (BN / 2) + j * 16 + ln) * 32 + quad * 8;
            bh[j] = *(const short8*)&sBh[off];
            bl[j] = *(const short8*)&sBl[off];
        }
#pragma unroll
        for (int i = 0; i < MT; ++i)
#pragma unroll
            for (int j = 0; j < NT; ++j) {
                acc[i][j] = __builtin_amdgcn_mfma_f32_16x16x32_bf16(ah[i], bh[j], acc[i][j], 0, 0, 0);
                acc[i][j] = __builtin_amdgcn_mfma_f32_16x16x32_bf16(ah[i], bl[j], acc[i][j], 0, 0, 0);
                acc[i][j] = __builtin_amdgcn_mfma_f32_16x16x32_bf16(al[i], bh[j], acc[i][j], 0, 0, 0);
            }
    }

#pragma unroll
    for (int i = 0; i < MT; ++i) {
#pragma unroll
        for (int r = 0; r < 4; ++r) {
            int gm = m0 + wm * (BM / 2) + i * 16 + quad * 4 + r;
            if (gm >= ROWS) continue;
            if (MODE == 0) {
                int jn = gm % 289;
                const float* Mrow = &aux[(size_t)jn * 256];
#pragma unroll
                for (int j = 0; j < NT; ++j) {
                    int gn = n0 + wn * (BN / 2) + j * 16 + ln;
                    out[(size_t)gm * 1280 + gn] = acc[i][j][r] * Mrow[gn & 255];
                }
            } else {
#pragma unroll
                for (int j = 0; j < NT; ++j) {
                    int gn = n0 + wn * (BN / 2) + j * 16 + ln;
                    out[(size_t)gm * 256 + gn] = acc[i][j][r] + aux[gn];
                }
            }
        }
    }
}

// ---------------- fused attention: scores + softmaxes + all combines -----
// 512 threads (8 waves) per (b,h), grid 512. LDS 63.5 KB.
// P3 is a split-bf16 MFMA GEMM: x_vsv[p,c] = sum_q P[p,q]*vsv[q,c],
// P[p=(j,n)][q=(k,m)] = aS[n][j][k] * aV[j][n][m]  (289x289 by 289x32).
// The MFMA 16x16x32 A-fragment (lane ln = row, quad*8 = k-offset) is built
// ENTIRELY in registers from aS/aV (8 products/lane, hi/lo bf16) — P never
// touches LDS. Only vsv is staged: transposed [c][q] bf16 hi/lo, K split in
// 2 halves of 160 to fit the buf region (LDS size unchanged).
// Round-4 hardening: q-index clamped to 288 before the /17 decode so every
// aS/aV access is in-bounds by construction (tail entries zeroed after).
__global__ __launch_bounds__(512, 2) void k_att(
    const float* __restrict__ qkv5,
    const float* __restrict__ A_s, const float* __restrict__ A_v,
    const float* __restrict__ adjS, const float* __restrict__ adjV,
    ushort_t* __restrict__ yhi, ushort_t* __restrict__ ylo)
{
    __shared__ __attribute__((aligned(16))) float sm[16184];
    float* aS  = sm;            // 4913  [n][j][k]
    float* aV  = sm + 4913;     // 4913  [j][n][m]
    float* ebS = sm + 9826;     // 289
    float* ebV = sm + 10115;    // 289
    float* buf = sm + 10404;    // 289*20 f32 (P1/P4/P5)  |  P3: vsv_t hi/lo

    const int t  = threadIdx.x;
    const int bh = blockIdx.x;
    const int b  = bh >> 3, h = bh & 7;
    const size_t rowbase = (size_t)b * 289;

    // ---- P0: exp of symmetrized biases ----
    for (int idx = t; idx < 578; idx += 512) {
        int f = idx / 289, rem = idx % 289;
        int jj = rem / 17, kk = rem % 17;
        float bias;
        if (f == 0)
            bias = 0.5f * ((A_s[jj*17+kk] + adjS[jj*17+kk]) + (A_s[kk*17+jj] + adjS[kk*17+jj]));
        else
            bias = 0.5f * ((A_v[jj*17+kk] + adjV[jj*17+kk]) + (A_v[kk*17+jj] + adjV[kk*17+jj]));
        (f ? ebV : ebS)[rem] = expf(bias);
    }

    // ---- P1: raw scores, LDS-accumulated across the 2 ch passes ----
    for (int ch = 0; ch < 2; ++ch) {
        __syncthreads();
        for (int idx = t; idx < 1156; idx += 512) {
            int p = idx >> 2, c = idx & 3;
            *(float4*)&buf[p * 20 + c * 4] =
                *(const float4*)&qkv5[(rowbase + p) * 1280 + 256 + h * 32 + ch * 16 + c * 4];
        }
        __syncthreads();
        for (int u = t; u < 578; u += 512) {
            const bool isS = (u < 289);
            const int p = isS ? u : u - 289;
            const float* qp = &qkv5[(rowbase + p) * 1280 + h * 32 + ch * 16];
            float4 q0 = *(const float4*)&qp[0];
            float4 q1 = *(const float4*)&qp[4];
            float4 q2 = *(const float4*)&qp[8];
            float4 q3 = *(const float4*)&qp[12];
            const int a = p / 17, bb = p % 17;
            float tmp[17];
            if (isS) {
#pragma unroll
                for (int kk = 0; kk < 17; ++kk) {
                    const float4* r = (const float4*)&buf[(kk * 17 + bb) * 20];
                    tmp[kk] = dot4(q0, r[0]) + dot4(q1, r[1]) + dot4(q2, r[2]) + dot4(q3, r[3]);
                }
                float* dst = &aS[bb * 289 + a * 17];
                if (ch == 0) {
#pragma unroll
                    for (int kk = 0; kk < 17; ++kk) dst[kk] = tmp[kk];
                } else {
#pragma unroll
                    for (int kk = 0; kk < 17; ++kk) dst[kk] += tmp[kk];
                }
            } else {
#pragma unroll
                for (int mm = 0; mm < 17; ++mm) {
                    const float4* r = (const float4*)&buf[(a * 17 + mm) * 20];
                    tmp[mm] = dot4(q0, r[0]) + dot4(q1, r[1]) + dot4(q2, r[2]) + dot4(q3, r[3]);
                }
                float* dst = &aV[a * 289 + bb * 17];
                if (ch == 0) {
#pragma unroll
                    for (int mm = 0; mm < 17; ++mm) dst[mm] = tmp[mm];
                } else {
#pragma unroll
                    for (int mm = 0; mm < 17; ++mm) dst[mm] += tmp[mm];
                }
            }
        }
    }
    __syncthreads();

    // ---- P2: in-place softmax on all 578 rows (SCALE folded in) ----
    for (int idx = t; idx < 578; idx += 512) {
        float* row = (idx < 289) ? &aS[idx * 17] : &aV[(idx - 289) * 17];
        float v[17];
#pragma unroll
        for (int kk = 0; kk < 17; ++kk) v[kk] = row[kk] * SCALE;
        float mx = v[0];
#pragma unroll
        for (int kk = 1; kk < 17; ++kk) mx = fmaxf(mx, v[kk]);
        float sum = 0.f;
#pragma unroll
        for (int kk = 0; kk < 17; ++kk) { v[kk] = expf(v[kk] - mx); sum += v[kk]; }
        float inv = 1.f / sum;
#pragma unroll
        for (int kk = 0; kk < 17; ++kk) row[kk] = v[kk] * inv;
    }
    // (no trailing sync: P3's staging sync orders P2 before consumers)

    // ---- P3: x_vsv via in-register-A split-bf16 MFMA ----
    {
        const int lane = t & 63;
        const int ln = lane & 15, quad = lane >> 4;
        const int wave = t >> 6;                  // 0..7
        ushort_t* vh = (ushort_t*)buf;            // [32][168] bf16 hi (pad 168)
        ushort_t* vl = vh + 32 * 168;             // lo

        f32x4 acc[3][2];
#pragma unroll
        for (int r = 0; r < 3; ++r) {
            acc[r][0] = (f32x4){0.f,0.f,0.f,0.f};
            acc[r][1] = (f32x4){0.f,0.f,0.f,0.f};
        }

        // per-lane row bases for the (up to) 3 row-tiles this wave owns
        int sbase[3], vbase[3];
#pragma unroll
        for (int r = 0; r < 3; ++r) {
            int p = (wave + 8 * r) * 16 + ln; if (p > 288) p = 288;
            int jj = (p * 61681) >> 20;           // p / 17
            int nn = p - jj * 17;
            sbase[r] = nn * 289 + jj * 17;        // aS row (n,j)
            vbase[r] = jj * 289 + nn * 17;        // aV row (j,n)
        }

        for (int khalf = 0; khalf < 2; ++khalf) {
            const int qbase = khalf * 160;
            const int V = khalf ? 129 : 160;      // valid q's this half
            __syncthreads();
            // zero pad (ql >= V); disjoint from valid-stage writes
            for (int e = t; e < 5376; e += 512) {
                if (e % 168 >= V) { vh[e] = 0; vl[e] = 0; }
            }
            // stage vsv transposed: vh/vl[c][ql], coalesced global reads
            for (int e = t; e < 32 * V; e += 512) {
                int ql = e >> 5, c = e & 31;
                float v = qkv5[(rowbase + qbase + ql) * 1280 + 1024 + h * 32 + c];
                ushort_t hh = f2bf(v);
                vh[c * 168 + ql] = hh;
                vl[c * 168 + ql] = f2bf(v - bf2f(hh));
            }
            __syncthreads();
#pragma unroll
            for (int kstep = 0; kstep < 5; ++kstep) {
                const int q0 = qbase + kstep * 32 + quad * 8;
                const int lb = kstep * 32 + quad * 8;
                short8 b0h = *(const short8*)&vh[ln * 168 + lb];
                short8 b0l = *(const short8*)&vl[ln * 168 + lb];
                short8 b1h = *(const short8*)&vh[(16 + ln) * 168 + lb];
                short8 b1l = *(const short8*)&vl[(16 + ln) * 168 + lb];
#pragma unroll
                for (int r = 0; r < 3; ++r) {
                    if (r == 2 && wave >= 3) continue;   // rt>=19: no output
                    short8 ah, al;
#pragma unroll
                    for (int i = 0; i < 8; ++i) {
                        int q = q0 + i;
                        int qc = (q < 289) ? q : 288;    // clamp: in-bounds decode
                        int k17 = (qc * 61681) >> 20;    // qc / 17
                        int m17 = qc - k17 * 17;
                        float pv = aS[sbase[r] + k17] * aV[vbase[r] + m17];
                        pv = (q < 289) ? pv : 0.f;
                        ushort_t ph = f2bf(pv);
                        ah[i] = (short)ph;
                        al[i] = (short)f2bf(pv - bf2f(ph));
                    }
                    acc[r][0] = __builtin_amdgcn_mfma_f32_16x16x32_bf16(ah, b0h, acc[r][0], 0, 0, 0);
                    acc[r][0] = __builtin_amdgcn_mfma_f32_16x16x32_bf16(ah, b0l, acc[r][0], 0, 0, 0);
                    acc[r][0] = __builtin_amdgcn_mfma_f32_16x16x32_bf16(al, b0h, acc[r][0], 0, 0, 0);
                    acc[r][1] = __builtin_amdgcn_mfma_f32_16x16x32_bf16(ah, b1h, acc[r][1], 0, 0, 0);
                    acc[r][1] = __builtin_amdgcn_mfma_f32_16x16x32_bf16(ah, b1l, acc[r][1], 0, 0, 0);
                    acc[r][1] = __builtin_amdgcn_mfma_f32_16x16x32_bf16(al, b1h, acc[r][1], 0, 0, 0);
                }
            }
        }
        // store: D row = rt*16 + quad*4 + rr, col = ct*16 + ln
#pragma unroll
        for (int r = 0; r < 3; ++r) {
            int rt = wave + 8 * r;
            if (rt >= 19) continue;
#pragma unroll
            for (int ct = 0; ct < 2; ++ct) {
#pragma unroll
                for (int rr = 0; rr < 4; ++rr) {
                    int p = rt * 16 + quad * 4 + rr;
                    if (p > 288) continue;
                    float v = acc[r][ct][rr];
                    ushort_t hh = f2bf(v);
                    size_t off = (rowbase + p) * 768 + h * 32 + ct * 16 + ln;
                    yhi[off] = hh;
                    ylo[off] = f2bf(v - bf2f(hh));
                }
            }
        }
    }

    // ---- P4: x_vs (aS2 = normalize(aS*ebS)) -> y cols 256..511 ----------
    for (int ch = 0; ch < 2; ++ch) {
        __syncthreads();
        for (int idx = t; idx < 1156; idx += 512) {
            int p = idx >> 2, c = idx & 3;
            *(float4*)&buf[p * 20 + c * 4] =
                *(const float4*)&qkv5[(rowbase + p) * 1280 + 512 + h * 32 + ch * 16 + c * 4];
        }
        __syncthreads();
        for (int u = t; u < 1156; u += 512) {
            const int c4 = (u & 3) * 4, rest = u >> 2;   // rest 0..288
            const int n = rest % 17, j = rest / 17;
            float w[17];
            float s = 0.f;
            const float* as = &aS[n * 289 + j * 17];
            const float* eb = &ebS[j * 17];
#pragma unroll
            for (int kk = 0; kk < 17; ++kk) { w[kk] = as[kk] * eb[kk]; s += w[kk]; }
            const float inv = 1.f / s;
            float4 a0 = {0,0,0,0};
            for (int kk = 0; kk < 17; ++kk) {
                float4 v = *(const float4*)&buf[(kk * 17 + n) * 20 + c4];
                fma4(a0, w[kk], v);
            }
            a0.x *= inv; a0.y *= inv; a0.z *= inv; a0.w *= inv;
            store_hilo(yhi, ylo, (rowbase + j * 17 + n) * 768 + 256 + h * 32 + ch * 16 + c4, a0);
        }
    }

    // ---- P5: x_vv (aV2 = normalize(aV*ebV)) -> y cols 512..767 ----------
    for (int ch = 0; ch < 2; ++ch) {
        __syncthreads();
        for (int idx = t; idx < 1156; idx += 512) {
            int p = idx >> 2, c = idx & 3;
            *(float4*)&buf[p * 20 + c * 4] =
                *(const float4*)&qkv5[(rowbase + p) * 1280 + 768 + h * 32 + ch * 16 + c * 4];
        }
        __syncthreads();
        for (int u = t; u < 1156; u += 512) {
            const int c4 = (u & 3) * 4, rest = u >> 2;   // rest 0..288
            const int j = rest % 17, n = rest / 17;
            float w[17];
            float s = 0.f;
            const float* av = &aV[j * 289 + n * 17];
            const float* eb = &ebV[n * 17];
#pragma unroll
            for (int mm = 0; mm < 17; ++mm) { w[mm] = av[mm] * eb[mm]; s += w[mm]; }
            const float inv = 1.f / s;
            float4 a0 = {0,0,0,0};
            for (int mm = 0; mm < 17; ++mm) {
                float4 v = *(const float4*)&buf[(j * 17 + mm) * 20 + c4];
                fma4(a0, w[mm], v);
            }
            a0.x *= inv; a0.y *= inv; a0.z *= inv; a0.w *= inv;
            store_hilo(yhi, ylo, (rowbase + j * 17 + n) * 768 + 512 + h * 32 + ch * 16 + c4, a0);
        }
    }
}

extern "C" void kernel_launch(void* const* d_in, const int* in_sizes, int n_in,
                              void* d_out, int out_size, void* d_ws, size_t ws_size,
                              hipStream_t stream)
{
    const float* x    = (const float*)d_in[0];
    const float* A_s  = (const float*)d_in[1];
    const float* A_v  = (const float*)d_in[2];
    const float* Wqkv = (const float*)d_in[3];
    const float* Wp   = (const float*)d_in[4];
    const float* bp   = (const float*)d_in[5];
    const float* M    = (const float*)d_in[6];
    const float* adjS = (const float*)d_in[7];
    const float* adjV = (const float*)d_in[8];
    float* out = (float*)d_out;

    char* w = (char*)d_ws;
    float*    qkv5  = (float*)w;                          // 95 MB, dead after k_att
    ushort_t* wph   = (ushort_t*)w;                       // written after k_att
    ushort_t* wpl   = (ushort_t*)(w + 393216);
    char* R = w + 134946816;
    ushort_t* xhi = (ushort_t*)R;
    ushort_t* xlo = (ushort_t*)(R + 9469952);
    ushort_t* wqh = (ushort_t*)(R + 18939904);
    ushort_t* wql = (ushort_t*)(R + 19595264);
    ushort_t* yhi = (ushort_t*)R;                         // alias (after qkv gemm done)
    ushort_t* ylo = (ushort_t*)(R + 28422144);

    k_cvt_xw<<<dim3(5904), 256, 0, stream>>>((const float4*)x, (ushort4*)xhi, (ushort4*)xlo,
                                             Wqkv, wqh, wql);
    k_gemm<128, 128, 256, 0><<<dim3(10, 145), 256, 0, stream>>>(xhi, xlo, wqh, wql, M, qkv5);
    k_att<<<dim3(512), 512, 0, stream>>>(qkv5, A_s, A_v, adjS, adjV, yhi, ylo);
    k_cvt_wp<<<dim3(256), 256, 0, stream>>>(Wp, wph, wpl);
    k_gemm<128, 64, 768, 1><<<dim3(4, 145), 256, 0, stream>>>(yhi, ylo, wph, wpl, bp, out);
}

// Round 6
// 276.528 us; speedup vs baseline: 1.1198x; 1.0760x over previous
//
#include <hip/hip_runtime.h>
#include <math.h>

#define ROWS 18496          // bt*J*N = 64*17*17
#define SCALE 0.17677669529663687f  // 1/sqrt(32)

typedef unsigned short ushort_t;
typedef __attribute__((ext_vector_type(8))) short short8;
typedef __attribute__((ext_vector_type(4))) float f32x4;

__device__ __forceinline__ void fma4(float4& d, float s, const float4& v) {
    d.x = fmaf(s, v.x, d.x); d.y = fmaf(s, v.y, d.y);
    d.z = fmaf(s, v.z, d.z); d.w = fmaf(s, v.w, d.w);
}
__device__ __forceinline__ float dot4(const float4& a, const float4& b) {
    return a.x*b.x + a.y*b.y + a.z*b.z + a.w*b.w;
}

__device__ __forceinline__ ushort_t f2bf(float x) {
    union { float f; unsigned u; } v; v.f = x;
    unsigned r = v.u + 0x7fffu + ((v.u >> 16) & 1u);
    return (ushort_t)(r >> 16);
}
__device__ __forceinline__ float bf2f(ushort_t b) {
    union { unsigned u; float f; } v; v.u = ((unsigned)b) << 16; return v.f;
}

__device__ __forceinline__ void gl_lds16(const void* g, void* l) {
    __builtin_amdgcn_global_load_lds(
        (const __attribute__((address_space(1))) void*)g,
        (__attribute__((address_space(3))) void*)l, 16, 0, 0);
}

__device__ __forceinline__ void store_hilo(ushort_t* yhi, ushort_t* ylo,
                                           size_t off, const float4& a)
{
    ushort4 h, l;
    h.x = f2bf(a.x); l.x = f2bf(a.x - bf2f(h.x));
    h.y = f2bf(a.y); l.y = f2bf(a.y - bf2f(h.y));
    h.z = f2bf(a.z); l.z = f2bf(a.z - bf2f(h.z));
    h.w = f2bf(a.w); l.w = f2bf(a.w - bf2f(h.w));
    *(ushort4*)&yhi[off] = h;
    *(ushort4*)&ylo[off] = l;
}

// ---------------- merged conversion kernel ----------------------------
__global__ __launch_bounds__(256) void k_cvt_xw(
    const float4* __restrict__ x, ushort4* __restrict__ xhi, ushort4* __restrict__ xlo,
    const float* __restrict__ W, ushort_t* __restrict__ bh, ushort_t* __restrict__ bl)
{
    if (blockIdx.x < 4624) {
        int i = blockIdx.x * 256 + threadIdx.x;
        float4 v = x[i];
        ushort4 h, l;
        h.x = f2bf(v.x); l.x = f2bf(v.x - bf2f(h.x));
        h.y = f2bf(v.y); l.y = f2bf(v.y - bf2f(h.y));
        h.z = f2bf(v.z); l.z = f2bf(v.z - bf2f(h.z));
        h.w = f2bf(v.w); l.w = f2bf(v.w - bf2f(h.w));
        xhi[i] = h; xlo[i] = l;
    } else {
        int o = blockIdx.x - 4624;   // 0..1279
        int kk = threadIdx.x;        // 0..255
        int col = (o & 255) * 5 + (o >> 8);
        float v = W[(size_t)kk * 1280 + col];
        ushort_t hh = f2bf(v);
        bh[(size_t)o * 256 + kk] = hh;
        bl[(size_t)o * 256 + kk] = f2bf(v - bf2f(hh));
    }
}

// Wp (768x256 f32) -> transposed bf16 [n][k]
__global__ __launch_bounds__(256) void k_cvt_wp(
    const float* __restrict__ W, ushort_t* __restrict__ bh, ushort_t* __restrict__ bl)
{
    int n = blockIdx.x;          // 0..255
    for (int k = threadIdx.x; k < 768; k += 256) {
        float v = W[(size_t)k * 256 + n];
        ushort_t h = f2bf(v);
        bh[(size_t)n * 768 + k] = h;
        bl[(size_t)n * 768 + k] = f2bf(v - bf2f(h));
    }
}

// ---------------- split-bf16 MFMA GEMM --------------------------------
template<int BM, int BN, int K, int MODE>
__global__ __launch_bounds__(256) void k_gemm(
    const ushort_t* __restrict__ Ahi, const ushort_t* __restrict__ Alo,
    const ushort_t* __restrict__ Bhi, const ushort_t* __restrict__ Blo,
    const float* __restrict__ aux,
    float* __restrict__ out)
{
    constexpr int MT = BM / 32;
    constexpr int NT = BN / 32;
    __shared__ __attribute__((aligned(16))) ushort_t sAh[BM * 32];
    __shared__ __attribute__((aligned(16))) ushort_t sAl[BM * 32];
    __shared__ __attribute__((aligned(16))) ushort_t sBh[BN * 32];
    __shared__ __attribute__((aligned(16))) ushort_t sBl[BN * 32];

    const int t = threadIdx.x;
    const int lane = t & 63;
    const int ln = lane & 15, quad = lane >> 4;
    const int wave = t >> 6;
    const int wm = wave >> 1, wn = wave & 1;
    const int m0 = blockIdx.y * BM, n0 = blockIdx.x * BN;

    f32x4 acc[MT][NT];
#pragma unroll
    for (int i = 0; i < MT; ++i)
#pragma unroll
        for (int j = 0; j < NT; ++j) acc[i][j] = (f32x4){0.f, 0.f, 0.f, 0.f};

    for (int kb = 0; kb < K; kb += 32) {
        __syncthreads();
#pragma unroll
        for (int s = t; s < BM * 4; s += 256) {
            int row = s >> 2, kc = s & 3;
            int gr = m0 + row; if (gr > ROWS - 1) gr = ROWS - 1;
            size_t gb = ((size_t)gr * K + kb) * 2 + kc * 16;
            int lb = (s & ~63) * 16;
            gl_lds16((const char*)Ahi + gb, (char*)sAh + lb);
            gl_lds16((const char*)Alo + gb, (char*)sAl + lb);
        }
#pragma unroll
        for (int s = t; s < BN * 4; s += 256) {
            int row = s >> 2, kc = s & 3;
            size_t gb = ((size_t)(n0 + row) * K + kb) * 2 + kc * 16;
            int lb = (s & ~63) * 16;
            gl_lds16((const char*)Bhi + gb, (char*)sBh + lb);
            gl_lds16((const char*)Blo + gb, (char*)sBl + lb);
        }
        __syncthreads();

        short8 ah[MT], al[MT], bh[NT], bl[NT];
#pragma unroll
        for (int i = 0; i < MT; ++i) {
            int off = (wm * (BM / 2) + i * 16 + ln) * 32 + quad * 8;
            ah[i] = *(const short8*)&sAh[off];
            al[i] = *(const short8*)&sAl[off];
        }
#pragma unroll
        for (int j = 0; j < NT; ++j) {
            int off = (wn * (BN / 2) + j * 16 + ln) * 32 + quad * 8;
            bh[j] = *(const short8*)&sBh[off];
            bl[j] = *(const short8*)&sBl[off];
        }
#pragma unroll
        for (int i = 0; i < MT; ++i)
#pragma unroll
            for (int j = 0; j < NT; ++j) {
                acc[i][j] = __builtin_amdgcn_mfma_f32_16x16x32_bf16(ah[i], bh[j], acc[i][j], 0, 0, 0);
                acc[i][j] = __builtin_amdgcn_mfma_f32_16x16x32_bf16(ah[i], bl[j], acc[i][j], 0, 0, 0);
                acc[i][j] = __builtin_amdgcn_mfma_f32_16x16x32_bf16(al[i], bh[j], acc[i][j], 0, 0, 0);
            }
    }

#pragma unroll
    for (int i = 0; i < MT; ++i) {
#pragma unroll
        for (int r = 0; r < 4; ++r) {
            int gm = m0 + wm * (BM / 2) + i * 16 + quad * 4 + r;
            if (gm >= ROWS) continue;
            if (MODE == 0) {
                int jn = gm % 289;
                const float* Mrow = &aux[(size_t)jn * 256];
#pragma unroll
                for (int j = 0; j < NT; ++j) {
                    int gn = n0 + wn * (BN / 2) + j * 16 + ln;
                    out[(size_t)gm * 1280 + gn] = acc[i][j][r] * Mrow[gn & 255];
                }
            } else {
#pragma unroll
                for (int j = 0; j < NT; ++j) {
                    int gn = n0 + wn * (BN / 2) + j * 16 + ln;
                    out[(size_t)gm * 256 + gn] = acc[i][j][r] + aux[gn];
                }
            }
        }
    }
}

// ---------------- fused attention: scores + softmaxes + all combines -----
// 512 threads (8 waves) per (b,h), grid 512. LDS 63.5 KB.
// OCCUPANCY PLAY (round 5 lesson): co-residency cliff is VGPR<=64 — round-1
// (VGPR 64, same LDS) ran 2 blocks/CU @44% occ; round-5 (VGPR 68) ran 1
// block @21%. So: (a) P3 inner loop restructured so only ONE ct's B-pair
// (8 VGPRs) is live at a time — B-frags re-read from LDS per (r,ct), which
// costs +8 ds_read_b128/kstep but drops peak live set to ~58; (b)
// __launch_bounds__(512,4) forces the 64-VGPR cap (round-1: arg 4 -> 64).
// Tripwire: FETCH_SIZE >> 50 MB means spill — revert to (512,2).
__global__ __launch_bounds__(512, 4) void k_att(
    const float* __restrict__ qkv5,
    const float* __restrict__ A_s, const float* __restrict__ A_v,
    const float* __restrict__ adjS, const float* __restrict__ adjV,
    ushort_t* __restrict__ yhi, ushort_t* __restrict__ ylo)
{
    __shared__ __attribute__((aligned(16))) float sm[16184];
    float* aS  = sm;            // 4913  [n][j][k]
    float* aV  = sm + 4913;     // 4913  [j][n][m]
    float* ebS = sm + 9826;     // 289
    float* ebV = sm + 10115;    // 289
    float* buf = sm + 10404;    // 289*20 f32 (P1/P4/P5)  |  P3: vsv_t hi/lo

    const int t  = threadIdx.x;
    const int bh = blockIdx.x;
    const int b  = bh >> 3, h = bh & 7;
    const size_t rowbase = (size_t)b * 289;

    // ---- P0: exp of symmetrized biases ----
    for (int idx = t; idx < 578; idx += 512) {
        int f = idx / 289, rem = idx % 289;
        int jj = rem / 17, kk = rem % 17;
        float bias;
        if (f == 0)
            bias = 0.5f * ((A_s[jj*17+kk] + adjS[jj*17+kk]) + (A_s[kk*17+jj] + adjS[kk*17+jj]));
        else
            bias = 0.5f * ((A_v[jj*17+kk] + adjV[jj*17+kk]) + (A_v[kk*17+jj] + adjV[kk*17+jj]));
        (f ? ebV : ebS)[rem] = expf(bias);
    }

    // ---- P1: raw scores, LDS-accumulated across the 2 ch passes ----
    for (int ch = 0; ch < 2; ++ch) {
        __syncthreads();
        for (int idx = t; idx < 1156; idx += 512) {
            int p = idx >> 2, c = idx & 3;
            *(float4*)&buf[p * 20 + c * 4] =
                *(const float4*)&qkv5[(rowbase + p) * 1280 + 256 + h * 32 + ch * 16 + c * 4];
        }
        __syncthreads();
        for (int u = t; u < 578; u += 512) {
            const bool isS = (u < 289);
            const int p = isS ? u : u - 289;
            const float* qp = &qkv5[(rowbase + p) * 1280 + h * 32 + ch * 16];
            float4 q0 = *(const float4*)&qp[0];
            float4 q1 = *(const float4*)&qp[4];
            float4 q2 = *(const float4*)&qp[8];
            float4 q3 = *(const float4*)&qp[12];
            const int a = p / 17, bb = p % 17;
            float tmp[17];
            if (isS) {
#pragma unroll
                for (int kk = 0; kk < 17; ++kk) {
                    const float4* r = (const float4*)&buf[(kk * 17 + bb) * 20];
                    tmp[kk] = dot4(q0, r[0]) + dot4(q1, r[1]) + dot4(q2, r[2]) + dot4(q3, r[3]);
                }
                float* dst = &aS[bb * 289 + a * 17];
                if (ch == 0) {
#pragma unroll
                    for (int kk = 0; kk < 17; ++kk) dst[kk] = tmp[kk];
                } else {
#pragma unroll
                    for (int kk = 0; kk < 17; ++kk) dst[kk] += tmp[kk];
                }
            } else {
#pragma unroll
                for (int mm = 0; mm < 17; ++mm) {
                    const float4* r = (const float4*)&buf[(a * 17 + mm) * 20];
                    tmp[mm] = dot4(q0, r[0]) + dot4(q1, r[1]) + dot4(q2, r[2]) + dot4(q3, r[3]);
                }
                float* dst = &aV[a * 289 + bb * 17];
                if (ch == 0) {
#pragma unroll
                    for (int mm = 0; mm < 17; ++mm) dst[mm] = tmp[mm];
                } else {
#pragma unroll
                    for (int mm = 0; mm < 17; ++mm) dst[mm] += tmp[mm];
                }
            }
        }
    }
    __syncthreads();

    // ---- P2: in-place softmax on all 578 rows (SCALE folded in) ----
    for (int idx = t; idx < 578; idx += 512) {
        float* row = (idx < 289) ? &aS[idx * 17] : &aV[(idx - 289) * 17];
        float v[17];
#pragma unroll
        for (int kk = 0; kk < 17; ++kk) v[kk] = row[kk] * SCALE;
        float mx = v[0];
#pragma unroll
        for (int kk = 1; kk < 17; ++kk) mx = fmaxf(mx, v[kk]);
        float sum = 0.f;
#pragma unroll
        for (int kk = 0; kk < 17; ++kk) { v[kk] = expf(v[kk] - mx); sum += v[kk]; }
        float inv = 1.f / sum;
#pragma unroll
        for (int kk = 0; kk < 17; ++kk) row[kk] = v[kk] * inv;
    }
    // (no trailing sync: P3's staging sync orders P2 before consumers)

    // ---- P3: x_vsv via in-register-A split-bf16 MFMA ----
    {
        const int lane = t & 63;
        const int ln = lane & 15, quad = lane >> 4;
        const int wave = t >> 6;                  // 0..7
        ushort_t* vh = (ushort_t*)buf;            // [32][168] bf16 hi (pad 168)
        ushort_t* vl = vh + 32 * 168;             // lo

        f32x4 acc[3][2];
#pragma unroll
        for (int r = 0; r < 3; ++r) {
            acc[r][0] = (f32x4){0.f,0.f,0.f,0.f};
            acc[r][1] = (f32x4){0.f,0.f,0.f,0.f};
        }

        // per-lane row bases for the (up to) 3 row-tiles this wave owns
        int sbase[3], vbase[3];
#pragma unroll
        for (int r = 0; r < 3; ++r) {
            int p = (wave + 8 * r) * 16 + ln; if (p > 288) p = 288;
            int jj = (p * 61681) >> 20;           // p / 17
            int nn = p - jj * 17;
            sbase[r] = nn * 289 + jj * 17;        // aS row (n,j)
            vbase[r] = jj * 289 + nn * 17;        // aV row (j,n)
        }

        for (int khalf = 0; khalf < 2; ++khalf) {
            const int qbase = khalf * 160;
            const int V = khalf ? 129 : 160;      // valid q's this half
            __syncthreads();
            // zero pad (ql >= V); disjoint from valid-stage writes
            for (int e = t; e < 5376; e += 512) {
                if (e % 168 >= V) { vh[e] = 0; vl[e] = 0; }
            }
            // stage vsv transposed: vh/vl[c][ql], coalesced global reads
            for (int e = t; e < 32 * V; e += 512) {
                int ql = e >> 5, c = e & 31;
                float v = qkv5[(rowbase + qbase + ql) * 1280 + 1024 + h * 32 + c];
                ushort_t hh = f2bf(v);
                vh[c * 168 + ql] = hh;
                vl[c * 168 + ql] = f2bf(v - bf2f(hh));
            }
            __syncthreads();
#pragma unroll
            for (int kstep = 0; kstep < 5; ++kstep) {
                const int q0 = qbase + kstep * 32 + quad * 8;
                const int lb = kstep * 32 + quad * 8;
#pragma unroll
                for (int r = 0; r < 3; ++r) {
                    if (r == 2 && wave >= 3) continue;   // rt>=19: no output
                    short8 ah, al;
#pragma unroll
                    for (int i = 0; i < 8; ++i) {
                        int q = q0 + i;
                        int qc = (q < 289) ? q : 288;    // clamp: in-bounds decode
                        int k17 = (qc * 61681) >> 20;    // qc / 17
                        int m17 = qc - k17 * 17;
                        float pv = aS[sbase[r] + k17] * aV[vbase[r] + m17];
                        pv = (q < 289) ? pv : 0.f;
                        ushort_t ph = f2bf(pv);
                        ah[i] = (short)ph;
                        al[i] = (short)f2bf(pv - bf2f(ph));
                    }
#pragma unroll
                    for (int ct = 0; ct < 2; ++ct) {
                        short8 bh8 = *(const short8*)&vh[(ct * 16 + ln) * 168 + lb];
                        short8 bl8 = *(const short8*)&vl[(ct * 16 + ln) * 168 + lb];
                        acc[r][ct] = __builtin_amdgcn_mfma_f32_16x16x32_bf16(ah, bh8, acc[r][ct], 0, 0, 0);
                        acc[r][ct] = __builtin_amdgcn_mfma_f32_16x16x32_bf16(ah, bl8, acc[r][ct], 0, 0, 0);
                        acc[r][ct] = __builtin_amdgcn_mfma_f32_16x16x32_bf16(al, bh8, acc[r][ct], 0, 0, 0);
                    }
                }
            }
        }
        // store: D row = rt*16 + quad*4 + rr, col = ct*16 + ln
#pragma unroll
        for (int r = 0; r < 3; ++r) {
            int rt = wave + 8 * r;
            if (rt >= 19) continue;
#pragma unroll
            for (int ct = 0; ct < 2; ++ct) {
#pragma unroll
                for (int rr = 0; rr < 4; ++rr) {
                    int p = rt * 16 + quad * 4 + rr;
                    if (p > 288) continue;
                    float v = acc[r][ct][rr];
                    ushort_t hh = f2bf(v);
                    size_t off = (rowbase + p) * 768 + h * 32 + ct * 16 + ln;
                    yhi[off] = hh;
                    ylo[off] = f2bf(v - bf2f(hh));
                }
            }
        }
    }

    // ---- P4: x_vs (aS2 = normalize(aS*ebS)) -> y cols 256..511 ----------
    for (int ch = 0; ch < 2; ++ch) {
        __syncthreads();
        for (int idx = t; idx < 1156; idx += 512) {
            int p = idx >> 2, c = idx & 3;
            *(float4*)&buf[p * 20 + c * 4] =
                *(const float4*)&qkv5[(rowbase + p) * 1280 + 512 + h * 32 + ch * 16 + c * 4];
        }
        __syncthreads();
        for (int u = t; u < 1156; u += 512) {
            const int c4 = (u & 3) * 4, rest = u >> 2;   // rest 0..288
            const int n = rest % 17, j = rest / 17;
            float w[17];
            float s = 0.f;
            const float* as = &aS[n * 289 + j * 17];
            const float* eb = &ebS[j * 17];
#pragma unroll
            for (int kk = 0; kk < 17; ++kk) { w[kk] = as[kk] * eb[kk]; s += w[kk]; }
            const float inv = 1.f / s;
            float4 a0 = {0,0,0,0};
            for (int kk = 0; kk < 17; ++kk) {
                float4 v = *(const float4*)&buf[(kk * 17 + n) * 20 + c4];
                fma4(a0, w[kk], v);
            }
            a0.x *= inv; a0.y *= inv; a0.z *= inv; a0.w *= inv;
            store_hilo(yhi, ylo, (rowbase + j * 17 + n) * 768 + 256 + h * 32 + ch * 16 + c4, a0);
        }
    }

    // ---- P5: x_vv (aV2 = normalize(aV*ebV)) -> y cols 512..767 ----------
    for (int ch = 0; ch < 2; ++ch) {
        __syncthreads();
        for (int idx = t; idx < 1156; idx += 512) {
            int p = idx >> 2, c = idx & 3;
            *(float4*)&buf[p * 20 + c * 4] =
                *(const float4*)&qkv5[(rowbase + p) * 1280 + 768 + h * 32 + ch * 16 + c * 4];
        }
        __syncthreads();
        for (int u = t; u < 1156; u += 512) {
            const int c4 = (u & 3) * 4, rest = u >> 2;   // rest 0..288
            const int j = rest % 17, n = rest / 17;
            float w[17];
            float s = 0.f;
            const float* av = &aV[j * 289 + n * 17];
            const float* eb = &ebV[n * 17];
#pragma unroll
            for (int mm = 0; mm < 17; ++mm) { w[mm] = av[mm] * eb[mm]; s += w[mm]; }
            const float inv = 1.f / s;
            float4 a0 = {0,0,0,0};
            for (int mm = 0; mm < 17; ++mm) {
                float4 v = *(const float4*)&buf[(j * 17 + mm) * 20 + c4];
                fma4(a0, w[mm], v);
            }
            a0.x *= inv; a0.y *= inv; a0.z *= inv; a0.w *= inv;
            store_hilo(yhi, ylo, (rowbase + j * 17 + n) * 768 + 512 + h * 32 + ch * 16 + c4, a0);
        }
    }
}

extern "C" void kernel_launch(void* const* d_in, const int* in_sizes, int n_in,
                              void* d_out, int out_size, void* d_ws, size_t ws_size,
                              hipStream_t stream)
{
    const float* x    = (const float*)d_in[0];
    const float* A_s  = (const float*)d_in[1];
    const float* A_v  = (const float*)d_in[2];
    const float* Wqkv = (const float*)d_in[3];
    const float* Wp   = (const float*)d_in[4];
    const float* bp   = (const float*)d_in[5];
    const float* M    = (const float*)d_in[6];
    const float* adjS = (const float*)d_in[7];
    const float* adjV = (const float*)d_in[8];
    float* out = (float*)d_out;

    char* w = (char*)d_ws;
    float*    qkv5  = (float*)w;                          // 95 MB, dead after k_att
    ushort_t* wph   = (ushort_t*)w;                       // written after k_att
    ushort_t* wpl   = (ushort_t*)(w + 393216);
    char* R = w + 134946816;
    ushort_t* xhi = (ushort_t*)R;
    ushort_t* xlo = (ushort_t*)(R + 9469952);
    ushort_t* wqh = (ushort_t*)(R + 18939904);
    ushort_t* wql = (ushort_t*)(R + 19595264);
    ushort_t* yhi = (ushort_t*)R;                         // alias (after qkv gemm done)
    ushort_t* ylo = (ushort_t*)(R + 28422144);

    k_cvt_xw<<<dim3(5904), 256, 0, stream>>>((const float4*)x, (ushort4*)xhi, (ushort4*)xlo,
                                             Wqkv, wqh, wql);
    k_gemm<128, 128, 256, 0><<<dim3(10, 145), 256, 0, stream>>>(xhi, xlo, wqh, wql, M, qkv5);
    k_att<<<dim3(512), 512, 0, stream>>>(qkv5, A_s, A_v, adjS, adjV, yhi, ylo);
    k_cvt_wp<<<dim3(256), 256, 0, stream>>>(Wp, wph, wpl);
    k_gemm<128, 64, 768, 1><<<dim3(4, 145), 256, 0, stream>>>(yhi, ylo, wph, wpl, bp, out);
}

// Round 7
// 273.028 us; speedup vs baseline: 1.1342x; 1.0128x over previous
//
#include <hip/hip_runtime.h>
#include <math.h>

#define ROWS 18496          // bt*J*N = 64*17*17
#define SCALE 0.17677669529663687f  // 1/sqrt(32)

typedef unsigned short ushort_t;
typedef __attribute__((ext_vector_type(8))) short short8;
typedef __attribute__((ext_vector_type(4))) float f32x4;

__device__ __forceinline__ void fma4(float4& d, float s, const float4& v) {
    d.x = fmaf(s, v.x, d.x); d.y = fmaf(s, v.y, d.y);
    d.z = fmaf(s, v.z, d.z); d.w = fmaf(s, v.w, d.w);
}
__device__ __forceinline__ float dot4(const float4& a, const float4& b) {
    return a.x*b.x + a.y*b.y + a.z*b.z + a.w*b.w;
}

__device__ __forceinline__ ushort_t f2bf(float x) {
    union { float f; unsigned u; } v; v.f = x;
    unsigned r = v.u + 0x7fffu + ((v.u >> 16) & 1u);
    return (ushort_t)(r >> 16);
}
__device__ __forceinline__ float bf2f(ushort_t b) {
    union { unsigned u; float f; } v; v.u = ((unsigned)b) << 16; return v.f;
}

__device__ __forceinline__ void gl_lds16(const void* g, void* l) {
    __builtin_amdgcn_global_load_lds(
        (const __attribute__((address_space(1))) void*)g,
        (__attribute__((address_space(3))) void*)l, 16, 0, 0);
}

__device__ __forceinline__ void store_hilo(ushort_t* yhi, ushort_t* ylo,
                                           size_t off, const float4& a)
{
    ushort4 h, l;
    h.x = f2bf(a.x); l.x = f2bf(a.x - bf2f(h.x));
    h.y = f2bf(a.y); l.y = f2bf(a.y - bf2f(h.y));
    h.z = f2bf(a.z); l.z = f2bf(a.z - bf2f(h.z));
    h.w = f2bf(a.w); l.w = f2bf(a.w - bf2f(h.w));
    *(ushort4*)&yhi[off] = h;
    *(ushort4*)&ylo[off] = l;
}

// ---------------- merged conversion kernel (x, Wqkv, Wp) ---------------
__global__ __launch_bounds__(256) void k_cvt_xw(
    const float4* __restrict__ x, ushort4* __restrict__ xhi, ushort4* __restrict__ xlo,
    const float* __restrict__ W, ushort_t* __restrict__ bh, ushort_t* __restrict__ bl,
    const float* __restrict__ Wp, ushort_t* __restrict__ wph, ushort_t* __restrict__ wpl)
{
    if (blockIdx.x < 4624) {
        int i = blockIdx.x * 256 + threadIdx.x;
        float4 v = x[i];
        ushort4 h, l;
        h.x = f2bf(v.x); l.x = f2bf(v.x - bf2f(h.x));
        h.y = f2bf(v.y); l.y = f2bf(v.y - bf2f(h.y));
        h.z = f2bf(v.z); l.z = f2bf(v.z - bf2f(h.z));
        h.w = f2bf(v.w); l.w = f2bf(v.w - bf2f(h.w));
        xhi[i] = h; xlo[i] = l;
    } else if (blockIdx.x < 5904) {
        int o = blockIdx.x - 4624;   // 0..1279
        int kk = threadIdx.x;        // 0..255
        int col = (o & 255) * 5 + (o >> 8);
        float v = W[(size_t)kk * 1280 + col];
        ushort_t hh = f2bf(v);
        bh[(size_t)o * 256 + kk] = hh;
        bl[(size_t)o * 256 + kk] = f2bf(v - bf2f(hh));
    } else {
        // Wp (768x256 f32) -> transposed bf16 [n][k]
        int n = blockIdx.x - 5904;   // 0..255
        for (int k = threadIdx.x; k < 768; k += 256) {
            float v = Wp[(size_t)k * 256 + n];
            ushort_t h = f2bf(v);
            wph[(size_t)n * 768 + k] = h;
            wpl[(size_t)n * 768 + k] = f2bf(v - bf2f(h));
        }
    }
}

// ---------------- split-bf16 MFMA GEMM --------------------------------
template<int BM, int BN, int K, int MODE>
__global__ __launch_bounds__(256) void k_gemm(
    const ushort_t* __restrict__ Ahi, const ushort_t* __restrict__ Alo,
    const ushort_t* __restrict__ Bhi, const ushort_t* __restrict__ Blo,
    const float* __restrict__ aux,
    float* __restrict__ out)
{
    constexpr int MT = BM / 32;
    constexpr int NT = BN / 32;
    __shared__ __attribute__((aligned(16))) ushort_t sAh[BM * 32];
    __shared__ __attribute__((aligned(16))) ushort_t sAl[BM * 32];
    __shared__ __attribute__((aligned(16))) ushort_t sBh[BN * 32];
    __shared__ __attribute__((aligned(16))) ushort_t sBl[BN * 32];

    const int t = threadIdx.x;
    const int lane = t & 63;
    const int ln = lane & 15, quad = lane >> 4;
    const int wave = t >> 6;
    const int wm = wave >> 1, wn = wave & 1;
    const int m0 = blockIdx.y * BM, n0 = blockIdx.x * BN;

    f32x4 acc[MT][NT];
#pragma unroll
    for (int i = 0; i < MT; ++i)
#pragma unroll
        for (int j = 0; j < NT; ++j) acc[i][j] = (f32x4){0.f, 0.f, 0.f, 0.f};

    for (int kb = 0; kb < K; kb += 32) {
        __syncthreads();
#pragma unroll
        for (int s = t; s < BM * 4; s += 256) {
            int row = s >> 2, kc = s & 3;
            int gr = m0 + row; if (gr > ROWS - 1) gr = ROWS - 1;
            size_t gb = ((size_t)gr * K + kb) * 2 + kc * 16;
            int lb = (s & ~63) * 16;
            gl_lds16((const char*)Ahi + gb, (char*)sAh + lb);
            gl_lds16((const char*)Alo + gb, (char*)sAl + lb);
        }
#pragma unroll
        for (int s = t; s < BN * 4; s += 256) {
            int row = s >> 2, kc = s & 3;
            size_t gb = ((size_t)(n0 + row) * K + kb) * 2 + kc * 16;
            int lb = (s & ~63) * 16;
            gl_lds16((const char*)Bhi + gb, (char*)sBh + lb);
            gl_lds16((const char*)Blo + gb, (char*)sBl + lb);
        }
        __syncthreads();

        short8 ah[MT], al[MT], bh[NT], bl[NT];
#pragma unroll
        for (int i = 0; i < MT; ++i) {
            int off = (wm * (BM / 2) + i * 16 + ln) * 32 + quad * 8;
            ah[i] = *(const short8*)&sAh[off];
            al[i] = *(const short8*)&sAl[off];
        }
#pragma unroll
        for (int j = 0; j < NT; ++j) {
            int off = (wn * (BN / 2) + j * 16 + ln) * 32 + quad * 8;
            bh[j] = *(const short8*)&sBh[off];
            bl[j] = *(const short8*)&sBl[off];
        }
#pragma unroll
        for (int i = 0; i < MT; ++i)
#pragma unroll
            for (int j = 0; j < NT; ++j) {
                acc[i][j] = __builtin_amdgcn_mfma_f32_16x16x32_bf16(ah[i], bh[j], acc[i][j], 0, 0, 0);
                acc[i][j] = __builtin_amdgcn_mfma_f32_16x16x32_bf16(ah[i], bl[j], acc[i][j], 0, 0, 0);
                acc[i][j] = __builtin_amdgcn_mfma_f32_16x16x32_bf16(al[i], bh[j], acc[i][j], 0, 0, 0);
            }
    }

#pragma unroll
    for (int i = 0; i < MT; ++i) {
#pragma unroll
        for (int r = 0; r < 4; ++r) {
            int gm = m0 + wm * (BM / 2) + i * 16 + quad * 4 + r;
            if (gm >= ROWS) continue;
            if (MODE == 0) {
                int jn = gm % 289;
                const float* Mrow = &aux[(size_t)jn * 256];
#pragma unroll
                for (int j = 0; j < NT; ++j) {
                    int gn = n0 + wn * (BN / 2) + j * 16 + ln;
                    out[(size_t)gm * 1280 + gn] = acc[i][j][r] * Mrow[gn & 255];
                }
            } else {
#pragma unroll
                for (int j = 0; j < NT; ++j) {
                    int gn = n0 + wn * (BN / 2) + j * 16 + ln;
                    out[(size_t)gm * 256 + gn] = acc[i][j][r] + aux[gn];
                }
            }
        }
    }
}

// ---------------- fused attention: scores + softmaxes + all combines -----
// 512 threads (8 waves) per (b,h), grid 512. LDS 63.5 KB, (512,4) = cap 64
// VGPR -> 2 blocks/CU (43% occ, round-6 verified). Round-6 spilled ~26
// floats/thread (FETCH 50->76 MB); round-7 register diet removes every hot
// >=17-element register array:
//  - P1: per-kk immediate LDS write/RMW (no tmp[17]).
//  - P2: 3-pass softmax over the LDS row (no v[17]).
//  - P3: khalf0 needs NO pad-zero (reads stop at col 159); khalf1 bulk
//    uint4 zero; A-build uses one div + increment-with-wrap (8<17 => <=1
//    wrap/run) instead of 8 magic-divs.
// Tripwire: FETCH >> 50 MB means still spilling.
__global__ __launch_bounds__(512, 4) void k_att(
    const float* __restrict__ qkv5,
    const float* __restrict__ A_s, const float* __restrict__ A_v,
    const float* __restrict__ adjS, const float* __restrict__ adjV,
    ushort_t* __restrict__ yhi, ushort_t* __restrict__ ylo)
{
    __shared__ __attribute__((aligned(16))) float sm[16184];
    float* aS  = sm;            // 4913  [n][j][k]
    float* aV  = sm + 4913;     // 4913  [j][n][m]
    float* ebS = sm + 9826;     // 289
    float* ebV = sm + 10115;    // 289
    float* buf = sm + 10404;    // 289*20 f32 (P1/P4/P5)  |  P3: vsv_t hi/lo

    const int t  = threadIdx.x;
    const int bh = blockIdx.x;
    const int b  = bh >> 3, h = bh & 7;
    const size_t rowbase = (size_t)b * 289;

    // ---- P0: exp of symmetrized biases ----
    for (int idx = t; idx < 578; idx += 512) {
        int f = idx / 289, rem = idx % 289;
        int jj = rem / 17, kk = rem % 17;
        float bias;
        if (f == 0)
            bias = 0.5f * ((A_s[jj*17+kk] + adjS[jj*17+kk]) + (A_s[kk*17+jj] + adjS[kk*17+jj]));
        else
            bias = 0.5f * ((A_v[jj*17+kk] + adjV[jj*17+kk]) + (A_v[kk*17+jj] + adjV[kk*17+jj]));
        (f ? ebV : ebS)[rem] = expf(bias);
    }

    // ---- P1: raw scores, accumulated directly in LDS (no reg arrays) ----
    for (int ch = 0; ch < 2; ++ch) {
        __syncthreads();
        for (int idx = t; idx < 1156; idx += 512) {
            int p = idx >> 2, c = idx & 3;
            *(float4*)&buf[p * 20 + c * 4] =
                *(const float4*)&qkv5[(rowbase + p) * 1280 + 256 + h * 32 + ch * 16 + c * 4];
        }
        __syncthreads();
        for (int u = t; u < 578; u += 512) {
            const bool isS = (u < 289);
            const int p = isS ? u : u - 289;
            const float* qp = &qkv5[(rowbase + p) * 1280 + h * 32 + ch * 16];
            float4 q0 = *(const float4*)&qp[0];
            float4 q1 = *(const float4*)&qp[4];
            float4 q2 = *(const float4*)&qp[8];
            float4 q3 = *(const float4*)&qp[12];
            const int a = p / 17, bb = p % 17;
            if (isS) {
                float* dst = &aS[bb * 289 + a * 17];
#pragma unroll
                for (int kk = 0; kk < 17; ++kk) {
                    const float4* r = (const float4*)&buf[(kk * 17 + bb) * 20];
                    float val = dot4(q0, r[0]) + dot4(q1, r[1]) + dot4(q2, r[2]) + dot4(q3, r[3]);
                    if (ch == 0) dst[kk] = val; else dst[kk] += val;
                }
            } else {
                float* dst = &aV[a * 289 + bb * 17];
#pragma unroll
                for (int mm = 0; mm < 17; ++mm) {
                    const float4* r = (const float4*)&buf[(a * 17 + mm) * 20];
                    float val = dot4(q0, r[0]) + dot4(q1, r[1]) + dot4(q2, r[2]) + dot4(q3, r[3]);
                    if (ch == 0) dst[mm] = val; else dst[mm] += val;
                }
            }
        }
    }
    __syncthreads();

    // ---- P2: in-place 3-pass softmax on all 578 rows (SCALE folded) ----
    for (int idx = t; idx < 578; idx += 512) {
        float* row = (idx < 289) ? &aS[idx * 17] : &aV[(idx - 289) * 17];
        float mx = row[0];
#pragma unroll
        for (int kk = 1; kk < 17; ++kk) mx = fmaxf(mx, row[kk]);
        float sum = 0.f;
#pragma unroll
        for (int kk = 0; kk < 17; ++kk) {
            float e = expf((row[kk] - mx) * SCALE);
            row[kk] = e; sum += e;
        }
        float inv = 1.f / sum;
#pragma unroll
        for (int kk = 0; kk < 17; ++kk) row[kk] *= inv;
    }
    // (no trailing sync: P3's staging sync orders P2 before consumers)

    // ---- P3: x_vsv via in-register-A split-bf16 MFMA ----
    {
        const int lane = t & 63;
        const int ln = lane & 15, quad = lane >> 4;
        const int wave = t >> 6;                  // 0..7
        ushort_t* vh = (ushort_t*)buf;            // [32][168] bf16 hi (pad 168)
        ushort_t* vl = vh + 32 * 168;             // lo

        f32x4 acc[3][2];
#pragma unroll
        for (int r = 0; r < 3; ++r) {
            acc[r][0] = (f32x4){0.f,0.f,0.f,0.f};
            acc[r][1] = (f32x4){0.f,0.f,0.f,0.f};
        }

        // per-lane row bases for the (up to) 3 row-tiles this wave owns
        int sbase[3], vbase[3];
#pragma unroll
        for (int r = 0; r < 3; ++r) {
            int p = (wave + 8 * r) * 16 + ln; if (p > 288) p = 288;
            int jj = (p * 61681) >> 20;           // p / 17
            int nn = p - jj * 17;
            sbase[r] = nn * 289 + jj * 17;        // aS row (n,j)
            vbase[r] = jj * 289 + nn * 17;        // aV row (j,n)
        }

        for (int khalf = 0; khalf < 2; ++khalf) {
            const int qbase = khalf * 160;
            const int V = khalf ? 129 : 160;      // valid q's this half
            __syncthreads();
            if (khalf == 1) {
                // bulk zero vh+vl (cols >=129 must be 0; reads reach col 159)
                uint4* z = (uint4*)vh;            // vh,vl contiguous: 1344 uint4
                for (int e = t; e < 1344; e += 512) z[e] = (uint4){0,0,0,0};
                __syncthreads();
            }
            // stage vsv transposed: vh/vl[c][ql], coalesced global reads
            for (int e = t; e < 32 * V; e += 512) {
                int ql = e >> 5, c = e & 31;
                float v = qkv5[(rowbase + qbase + ql) * 1280 + 1024 + h * 32 + c];
                ushort_t hh = f2bf(v);
                vh[c * 168 + ql] = hh;
                vl[c * 168 + ql] = f2bf(v - bf2f(hh));
            }
            __syncthreads();
#pragma unroll
            for (int kstep = 0; kstep < 5; ++kstep) {
                const int q0 = qbase + kstep * 32 + quad * 8;
                const int lb = kstep * 32 + quad * 8;
#pragma unroll
                for (int r = 0; r < 3; ++r) {
                    if (r == 2 && wave >= 3) continue;   // rt>=19: no output
                    short8 ah, al;
                    int qc0 = (q0 < 289) ? q0 : 288;
                    int k17 = (qc0 * 61681) >> 20;       // qc0 / 17
                    int m17 = qc0 - k17 * 17;
#pragma unroll
                    for (int i = 0; i < 8; ++i) {
                        float pv = aS[sbase[r] + k17] * aV[vbase[r] + m17];
                        pv = (q0 + i < 289) ? pv : 0.f;
                        ushort_t ph = f2bf(pv);
                        ah[i] = (short)ph;
                        al[i] = (short)f2bf(pv - bf2f(ph));
                        // increment (k17,m17) with single possible wrap (8<17)
                        ++m17;
                        if (m17 == 17) { m17 = 0; ++k17; }
                    }
#pragma unroll
                    for (int ct = 0; ct < 2; ++ct) {
                        short8 bh8 = *(const short8*)&vh[(ct * 16 + ln) * 168 + lb];
                        short8 bl8 = *(const short8*)&vl[(ct * 16 + ln) * 168 + lb];
                        acc[r][ct] = __builtin_amdgcn_mfma_f32_16x16x32_bf16(ah, bh8, acc[r][ct], 0, 0, 0);
                        acc[r][ct] = __builtin_amdgcn_mfma_f32_16x16x32_bf16(ah, bl8, acc[r][ct], 0, 0, 0);
                        acc[r][ct] = __builtin_amdgcn_mfma_f32_16x16x32_bf16(al, bh8, acc[r][ct], 0, 0, 0);
                    }
                }
            }
        }
        // store: D row = rt*16 + quad*4 + rr, col = ct*16 + ln
#pragma unroll
        for (int r = 0; r < 3; ++r) {
            int rt = wave + 8 * r;
            if (rt >= 19) continue;
#pragma unroll
            for (int ct = 0; ct < 2; ++ct) {
#pragma unroll
                for (int rr = 0; rr < 4; ++rr) {
                    int p = rt * 16 + quad * 4 + rr;
                    if (p > 288) continue;
                    float v = acc[r][ct][rr];
                    ushort_t hh = f2bf(v);
                    size_t off = (rowbase + p) * 768 + h * 32 + ct * 16 + ln;
                    yhi[off] = hh;
                    ylo[off] = f2bf(v - bf2f(hh));
                }
            }
        }
    }

    // ---- P4: x_vs (aS2 = normalize(aS*ebS)) -> y cols 256..511 ----------
    for (int ch = 0; ch < 2; ++ch) {
        __syncthreads();
        for (int idx = t; idx < 1156; idx += 512) {
            int p = idx >> 2, c = idx & 3;
            *(float4*)&buf[p * 20 + c * 4] =
                *(const float4*)&qkv5[(rowbase + p) * 1280 + 512 + h * 32 + ch * 16 + c * 4];
        }
        __syncthreads();
        for (int u = t; u < 1156; u += 512) {
            const int c4 = (u & 3) * 4, rest = u >> 2;   // rest 0..288
            const int n = rest % 17, j = rest / 17;
            float w[17];
            float s = 0.f;
            const float* as = &aS[n * 289 + j * 17];
            const float* eb = &ebS[j * 17];
#pragma unroll
            for (int kk = 0; kk < 17; ++kk) { w[kk] = as[kk] * eb[kk]; s += w[kk]; }
            const float inv = 1.f / s;
            float4 a0 = {0,0,0,0};
            for (int kk = 0; kk < 17; ++kk) {
                float4 v = *(const float4*)&buf[(kk * 17 + n) * 20 + c4];
                fma4(a0, w[kk], v);
            }
            a0.x *= inv; a0.y *= inv; a0.z *= inv; a0.w *= inv;
            store_hilo(yhi, ylo, (rowbase + j * 17 + n) * 768 + 256 + h * 32 + ch * 16 + c4, a0);
        }
    }

    // ---- P5: x_vv (aV2 = normalize(aV*ebV)) -> y cols 512..767 ----------
    for (int ch = 0; ch < 2; ++ch) {
        __syncthreads();
        for (int idx = t; idx < 1156; idx += 512) {
            int p = idx >> 2, c = idx & 3;
            *(float4*)&buf[p * 20 + c * 4] =
                *(const float4*)&qkv5[(rowbase + p) * 1280 + 768 + h * 32 + ch * 16 + c * 4];
        }
        __syncthreads();
        for (int u = t; u < 1156; u += 512) {
            const int c4 = (u & 3) * 4, rest = u >> 2;   // rest 0..288
            const int j = rest % 17, n = rest / 17;
            float w[17];
            float s = 0.f;
            const float* av = &aV[j * 289 + n * 17];
            const float* eb = &ebV[n * 17];
#pragma unroll
            for (int mm = 0; mm < 17; ++mm) { w[mm] = av[mm] * eb[mm]; s += w[mm]; }
            const float inv = 1.f / s;
            float4 a0 = {0,0,0,0};
            for (int mm = 0; mm < 17; ++mm) {
                float4 v = *(const float4*)&buf[(j * 17 + mm) * 20 + c4];
                fma4(a0, w[mm], v);
            }
            a0.x *= inv; a0.y *= inv; a0.z *= inv; a0.w *= inv;
            store_hilo(yhi, ylo, (rowbase + j * 17 + n) * 768 + 512 + h * 32 + ch * 16 + c4, a0);
        }
    }
}

extern "C" void kernel_launch(void* const* d_in, const int* in_sizes, int n_in,
                              void* d_out, int out_size, void* d_ws, size_t ws_size,
                              hipStream_t stream)
{
    const float* x    = (const float*)d_in[0];
    const float* A_s  = (const float*)d_in[1];
    const float* A_v  = (const float*)d_in[2];
    const float* Wqkv = (const float*)d_in[3];
    const float* Wp   = (const float*)d_in[4];
    const float* bp   = (const float*)d_in[5];
    const float* M    = (const float*)d_in[6];
    const float* adjS = (const float*)d_in[7];
    const float* adjV = (const float*)d_in[8];
    float* out = (float*)d_out;

    char* w = (char*)d_ws;
    float*    qkv5  = (float*)w;                          // 94.7 MB, dead after k_att
    // wph/wpl live in the dead gap between qkv5 end (94,699,520) and R —
    // written by k_cvt_xw (before GEMM1 writes qkv5? no: written first, and
    // GEMM1's qkv5 writes stop at 94,699,520 so no clobber).
    ushort_t* wph   = (ushort_t*)(w + 94699520);
    ushort_t* wpl   = (ushort_t*)(w + 94699520 + 393216);
    char* R = w + 134946816;
    ushort_t* xhi = (ushort_t*)R;
    ushort_t* xlo = (ushort_t*)(R + 9469952);
    ushort_t* wqh = (ushort_t*)(R + 18939904);
    ushort_t* wql = (ushort_t*)(R + 19595264);
    ushort_t* yhi = (ushort_t*)R;                         // alias (after qkv gemm done)
    ushort_t* ylo = (ushort_t*)(R + 28422144);

    k_cvt_xw<<<dim3(6160), 256, 0, stream>>>((const float4*)x, (ushort4*)xhi, (ushort4*)xlo,
                                             Wqkv, wqh, wql, Wp, wph, wpl);
    k_gemm<128, 128, 256, 0><<<dim3(10, 145), 256, 0, stream>>>(xhi, xlo, wqh, wql, M, qkv5);
    k_att<<<dim3(512), 512, 0, stream>>>(qkv5, A_s, A_v, adjS, adjV, yhi, ylo);
    k_gemm<128, 64, 768, 1><<<dim3(4, 145), 256, 0, stream>>>(yhi, ylo, wph, wpl, bp, out);
}

// Round 8
// 255.083 us; speedup vs baseline: 1.2140x; 1.0704x over previous
//
#include <hip/hip_runtime.h>
#include <math.h>

#define ROWS 18496          // bt*J*N = 64*17*17
#define SCALE 0.17677669529663687f  // 1/sqrt(32)

typedef unsigned short ushort_t;
typedef __attribute__((ext_vector_type(8))) short short8;
typedef __attribute__((ext_vector_type(4))) float f32x4;

__device__ __forceinline__ void fma4(float4& d, float s, const float4& v) {
    d.x = fmaf(s, v.x, d.x); d.y = fmaf(s, v.y, d.y);
    d.z = fmaf(s, v.z, d.z); d.w = fmaf(s, v.w, d.w);
}
__device__ __forceinline__ float dot4(const float4& a, const float4& b) {
    return a.x*b.x + a.y*b.y + a.z*b.z + a.w*b.w;
}

__device__ __forceinline__ ushort_t f2bf(float x) {
    union { float f; unsigned u; } v; v.f = x;
    unsigned r = v.u + 0x7fffu + ((v.u >> 16) & 1u);
    return (ushort_t)(r >> 16);
}
__device__ __forceinline__ float bf2f(ushort_t b) {
    union { unsigned u; float f; } v; v.u = ((unsigned)b) << 16; return v.f;
}

__device__ __forceinline__ void gl_lds16(const void* g, void* l) {
    __builtin_amdgcn_global_load_lds(
        (const __attribute__((address_space(1))) void*)g,
        (__attribute__((address_space(3))) void*)l, 16, 0, 0);
}

__device__ __forceinline__ void store_hilo(ushort_t* yhi, ushort_t* ylo,
                                           size_t off, const float4& a)
{
    ushort4 h, l;
    h.x = f2bf(a.x); l.x = f2bf(a.x - bf2f(h.x));
    h.y = f2bf(a.y); l.y = f2bf(a.y - bf2f(h.y));
    h.z = f2bf(a.z); l.z = f2bf(a.z - bf2f(h.z));
    h.w = f2bf(a.w); l.w = f2bf(a.w - bf2f(h.w));
    *(ushort4*)&yhi[off] = h;
    *(ushort4*)&ylo[off] = l;
}

// ---------------- merged conversion kernel (x, Wqkv, Wp) ---------------
__global__ __launch_bounds__(256) void k_cvt_xw(
    const float4* __restrict__ x, ushort4* __restrict__ xhi, ushort4* __restrict__ xlo,
    const float* __restrict__ W, ushort_t* __restrict__ bh, ushort_t* __restrict__ bl,
    const float* __restrict__ Wp, ushort_t* __restrict__ wph, ushort_t* __restrict__ wpl)
{
    if (blockIdx.x < 4624) {
        int i = blockIdx.x * 256 + threadIdx.x;
        float4 v = x[i];
        ushort4 h, l;
        h.x = f2bf(v.x); l.x = f2bf(v.x - bf2f(h.x));
        h.y = f2bf(v.y); l.y = f2bf(v.y - bf2f(h.y));
        h.z = f2bf(v.z); l.z = f2bf(v.z - bf2f(h.z));
        h.w = f2bf(v.w); l.w = f2bf(v.w - bf2f(h.w));
        xhi[i] = h; xlo[i] = l;
    } else if (blockIdx.x < 5904) {
        int o = blockIdx.x - 4624;   // 0..1279
        int kk = threadIdx.x;        // 0..255
        int col = (o & 255) * 5 + (o >> 8);
        float v = W[(size_t)kk * 1280 + col];
        ushort_t hh = f2bf(v);
        bh[(size_t)o * 256 + kk] = hh;
        bl[(size_t)o * 256 + kk] = f2bf(v - bf2f(hh));
    } else {
        // Wp (768x256 f32) -> transposed bf16 [n][k]
        int n = blockIdx.x - 5904;   // 0..255
        for (int k = threadIdx.x; k < 768; k += 256) {
            float v = Wp[(size_t)k * 256 + n];
            ushort_t h = f2bf(v);
            wph[(size_t)n * 768 + k] = h;
            wpl[(size_t)n * 768 + k] = f2bf(v - bf2f(h));
        }
    }
}

// ---------------- split-bf16 MFMA GEMM --------------------------------
// Round-8: XCD-aware bijective block remap (T1 + m204 bijective form).
// HW round-robins linear wgid across the 8 XCD L2s; consecutive LOGICAL
// blocks share the same A-tile (grid.x = N-tiles is the fast dim), so
// remapping each XCD to a contiguous logical chunk gives ~GX-fold A reuse
// in its private L2 (A re-read was ~379 MB for GEMM1, ~227 MB for GEMM2).
template<int BM, int BN, int K, int MODE>
__global__ __launch_bounds__(256) void k_gemm(
    const ushort_t* __restrict__ Ahi, const ushort_t* __restrict__ Alo,
    const ushort_t* __restrict__ Bhi, const ushort_t* __restrict__ Blo,
    const float* __restrict__ aux,
    float* __restrict__ out)
{
    constexpr int MT = BM / 32;
    constexpr int NT = BN / 32;
    __shared__ __attribute__((aligned(16))) ushort_t sAh[BM * 32];
    __shared__ __attribute__((aligned(16))) ushort_t sAl[BM * 32];
    __shared__ __attribute__((aligned(16))) ushort_t sBh[BN * 32];
    __shared__ __attribute__((aligned(16))) ushort_t sBl[BN * 32];

    const int t = threadIdx.x;
    const int lane = t & 63;
    const int ln = lane & 15, quad = lane >> 4;
    const int wave = t >> 6;
    const int wm = wave >> 1, wn = wave & 1;

    // bijective XCD remap: wgid%8 = XCD (HW round-robin); XCD k owns the
    // contiguous logical range [base(k), base(k)+count(k))
    const int nwg = (int)(gridDim.x * gridDim.y);
    int wgid = (int)(blockIdx.y * gridDim.x + blockIdx.x);
    int q = nwg >> 3, r = nwg & 7;
    int xcd = wgid & 7, i0 = wgid >> 3;
    int base = (xcd < r) ? xcd * (q + 1) : r * (q + 1) + (xcd - r) * q;
    int logical = base + i0;
    const int m0 = (logical / (int)gridDim.x) * BM;
    const int n0 = (logical % (int)gridDim.x) * BN;

    f32x4 acc[MT][NT];
#pragma unroll
    for (int i = 0; i < MT; ++i)
#pragma unroll
        for (int j = 0; j < NT; ++j) acc[i][j] = (f32x4){0.f, 0.f, 0.f, 0.f};

    for (int kb = 0; kb < K; kb += 32) {
        __syncthreads();
#pragma unroll
        for (int s = t; s < BM * 4; s += 256) {
            int row = s >> 2, kc = s & 3;
            int gr = m0 + row; if (gr > ROWS - 1) gr = ROWS - 1;
            size_t gb = ((size_t)gr * K + kb) * 2 + kc * 16;
            int lb = (s & ~63) * 16;
            gl_lds16((const char*)Ahi + gb, (char*)sAh + lb);
            gl_lds16((const char*)Alo + gb, (char*)sAl + lb);
        }
#pragma unroll
        for (int s = t; s < BN * 4; s += 256) {
            int row = s >> 2, kc = s & 3;
            size_t gb = ((size_t)(n0 + row) * K + kb) * 2 + kc * 16;
            int lb = (s & ~63) * 16;
            gl_lds16((const char*)Bhi + gb, (char*)sBh + lb);
            gl_lds16((const char*)Blo + gb, (char*)sBl + lb);
        }
        __syncthreads();

        short8 ah[MT], al[MT], bh[NT], bl[NT];
#pragma unroll
        for (int i = 0; i < MT; ++i) {
            int off = (wm * (BM / 2) + i * 16 + ln) * 32 + quad * 8;
            ah[i] = *(const short8*)&sAh[off];
            al[i] = *(const short8*)&sAl[off];
        }
#pragma unroll
        for (int j = 0; j < NT; ++j) {
            int off = (wn * (BN / 2) + j * 16 + ln) * 32 + quad * 8;
            bh[j] = *(const short8*)&sBh[off];
            bl[j] = *(const short8*)&sBl[off];
        }
#pragma unroll
        for (int i = 0; i < MT; ++i)
#pragma unroll
            for (int j = 0; j < NT; ++j) {
                acc[i][j] = __builtin_amdgcn_mfma_f32_16x16x32_bf16(ah[i], bh[j], acc[i][j], 0, 0, 0);
                acc[i][j] = __builtin_amdgcn_mfma_f32_16x16x32_bf16(ah[i], bl[j], acc[i][j], 0, 0, 0);
                acc[i][j] = __builtin_amdgcn_mfma_f32_16x16x32_bf16(al[i], bh[j], acc[i][j], 0, 0, 0);
            }
    }

#pragma unroll
    for (int i = 0; i < MT; ++i) {
#pragma unroll
        for (int r2 = 0; r2 < 4; ++r2) {
            int gm = m0 + wm * (BM / 2) + i * 16 + quad * 4 + r2;
            if (gm >= ROWS) continue;
            if (MODE == 0) {
                int jn = gm % 289;
                const float* Mrow = &aux[(size_t)jn * 256];
#pragma unroll
                for (int j = 0; j < NT; ++j) {
                    int gn = n0 + wn * (BN / 2) + j * 16 + ln;
                    out[(size_t)gm * 1280 + gn] = acc[i][j][r2] * Mrow[gn & 255];
                }
            } else {
#pragma unroll
                for (int j = 0; j < NT; ++j) {
                    int gn = n0 + wn * (BN / 2) + j * 16 + ln;
                    out[(size_t)gm * 256 + gn] = acc[i][j][r2] + aux[gn];
                }
            }
        }
    }
}

// ---------------- fused attention: scores + softmaxes + all combines -----
// 512 threads (8 waves) per (b,h), grid 512. LDS 63.5 KB, (512,4) = 64 VGPR
// cap -> 2 blocks/CU. Round-8: P4/P5 lose their w[17] register array (the
// last ~8.6 MB of scratch spill): sum pass first, then recompute as*eb in
// the fma loop. Everything else as round-7.
__global__ __launch_bounds__(512, 4) void k_att(
    const float* __restrict__ qkv5,
    const float* __restrict__ A_s, const float* __restrict__ A_v,
    const float* __restrict__ adjS, const float* __restrict__ adjV,
    ushort_t* __restrict__ yhi, ushort_t* __restrict__ ylo)
{
    __shared__ __attribute__((aligned(16))) float sm[16184];
    float* aS  = sm;            // 4913  [n][j][k]
    float* aV  = sm + 4913;     // 4913  [j][n][m]
    float* ebS = sm + 9826;     // 289
    float* ebV = sm + 10115;    // 289
    float* buf = sm + 10404;    // 289*20 f32 (P1/P4/P5)  |  P3: vsv_t hi/lo

    const int t  = threadIdx.x;
    const int bh = blockIdx.x;
    const int b  = bh >> 3, h = bh & 7;
    const size_t rowbase = (size_t)b * 289;

    // ---- P0: exp of symmetrized biases ----
    for (int idx = t; idx < 578; idx += 512) {
        int f = idx / 289, rem = idx % 289;
        int jj = rem / 17, kk = rem % 17;
        float bias;
        if (f == 0)
            bias = 0.5f * ((A_s[jj*17+kk] + adjS[jj*17+kk]) + (A_s[kk*17+jj] + adjS[kk*17+jj]));
        else
            bias = 0.5f * ((A_v[jj*17+kk] + adjV[jj*17+kk]) + (A_v[kk*17+jj] + adjV[kk*17+jj]));
        (f ? ebV : ebS)[rem] = expf(bias);
    }

    // ---- P1: raw scores, accumulated directly in LDS (no reg arrays) ----
    for (int ch = 0; ch < 2; ++ch) {
        __syncthreads();
        for (int idx = t; idx < 1156; idx += 512) {
            int p = idx >> 2, c = idx & 3;
            *(float4*)&buf[p * 20 + c * 4] =
                *(const float4*)&qkv5[(rowbase + p) * 1280 + 256 + h * 32 + ch * 16 + c * 4];
        }
        __syncthreads();
        for (int u = t; u < 578; u += 512) {
            const bool isS = (u < 289);
            const int p = isS ? u : u - 289;
            const float* qp = &qkv5[(rowbase + p) * 1280 + h * 32 + ch * 16];
            float4 q0 = *(const float4*)&qp[0];
            float4 q1 = *(const float4*)&qp[4];
            float4 q2 = *(const float4*)&qp[8];
            float4 q3 = *(const float4*)&qp[12];
            const int a = p / 17, bb = p % 17;
            if (isS) {
                float* dst = &aS[bb * 289 + a * 17];
#pragma unroll
                for (int kk = 0; kk < 17; ++kk) {
                    const float4* r = (const float4*)&buf[(kk * 17 + bb) * 20];
                    float val = dot4(q0, r[0]) + dot4(q1, r[1]) + dot4(q2, r[2]) + dot4(q3, r[3]);
                    if (ch == 0) dst[kk] = val; else dst[kk] += val;
                }
            } else {
                float* dst = &aV[a * 289 + bb * 17];
#pragma unroll
                for (int mm = 0; mm < 17; ++mm) {
                    const float4* r = (const float4*)&buf[(a * 17 + mm) * 20];
                    float val = dot4(q0, r[0]) + dot4(q1, r[1]) + dot4(q2, r[2]) + dot4(q3, r[3]);
                    if (ch == 0) dst[mm] = val; else dst[mm] += val;
                }
            }
        }
    }
    __syncthreads();

    // ---- P2: in-place 3-pass softmax on all 578 rows (SCALE folded) ----
    for (int idx = t; idx < 578; idx += 512) {
        float* row = (idx < 289) ? &aS[idx * 17] : &aV[(idx - 289) * 17];
        float mx = row[0];
#pragma unroll
        for (int kk = 1; kk < 17; ++kk) mx = fmaxf(mx, row[kk]);
        float sum = 0.f;
#pragma unroll
        for (int kk = 0; kk < 17; ++kk) {
            float e = expf((row[kk] - mx) * SCALE);
            row[kk] = e; sum += e;
        }
        float inv = 1.f / sum;
#pragma unroll
        for (int kk = 0; kk < 17; ++kk) row[kk] *= inv;
    }
    // (no trailing sync: P3's staging sync orders P2 before consumers)

    // ---- P3: x_vsv via in-register-A split-bf16 MFMA ----
    {
        const int lane = t & 63;
        const int ln = lane & 15, quad = lane >> 4;
        const int wave = t >> 6;                  // 0..7
        ushort_t* vh = (ushort_t*)buf;            // [32][168] bf16 hi (pad 168)
        ushort_t* vl = vh + 32 * 168;             // lo

        f32x4 acc[3][2];
#pragma unroll
        for (int r = 0; r < 3; ++r) {
            acc[r][0] = (f32x4){0.f,0.f,0.f,0.f};
            acc[r][1] = (f32x4){0.f,0.f,0.f,0.f};
        }

        // per-lane row bases for the (up to) 3 row-tiles this wave owns
        int sbase[3], vbase[3];
#pragma unroll
        for (int r = 0; r < 3; ++r) {
            int p = (wave + 8 * r) * 16 + ln; if (p > 288) p = 288;
            int jj = (p * 61681) >> 20;           // p / 17
            int nn = p - jj * 17;
            sbase[r] = nn * 289 + jj * 17;        // aS row (n,j)
            vbase[r] = jj * 289 + nn * 17;        // aV row (j,n)
        }

        for (int khalf = 0; khalf < 2; ++khalf) {
            const int qbase = khalf * 160;
            const int V = khalf ? 129 : 160;      // valid q's this half
            __syncthreads();
            if (khalf == 1) {
                // bulk zero vh+vl (cols >=129 must be 0; reads reach col 159)
                uint4* z = (uint4*)vh;            // vh,vl contiguous: 1344 uint4
                for (int e = t; e < 1344; e += 512) z[e] = (uint4){0,0,0,0};
                __syncthreads();
            }
            // stage vsv transposed: vh/vl[c][ql], coalesced global reads
            for (int e = t; e < 32 * V; e += 512) {
                int ql = e >> 5, c = e & 31;
                float v = qkv5[(rowbase + qbase + ql) * 1280 + 1024 + h * 32 + c];
                ushort_t hh = f2bf(v);
                vh[c * 168 + ql] = hh;
                vl[c * 168 + ql] = f2bf(v - bf2f(hh));
            }
            __syncthreads();
#pragma unroll
            for (int kstep = 0; kstep < 5; ++kstep) {
                const int q0 = qbase + kstep * 32 + quad * 8;
                const int lb = kstep * 32 + quad * 8;
#pragma unroll
                for (int r = 0; r < 3; ++r) {
                    if (r == 2 && wave >= 3) continue;   // rt>=19: no output
                    short8 ah, al;
                    int qc0 = (q0 < 289) ? q0 : 288;
                    int k17 = (qc0 * 61681) >> 20;       // qc0 / 17
                    int m17 = qc0 - k17 * 17;
#pragma unroll
                    for (int i = 0; i < 8; ++i) {
                        float pv = aS[sbase[r] + k17] * aV[vbase[r] + m17];
                        pv = (q0 + i < 289) ? pv : 0.f;
                        ushort_t ph = f2bf(pv);
                        ah[i] = (short)ph;
                        al[i] = (short)f2bf(pv - bf2f(ph));
                        // increment (k17,m17) with single possible wrap (8<17)
                        ++m17;
                        if (m17 == 17) { m17 = 0; ++k17; }
                    }
#pragma unroll
                    for (int ct = 0; ct < 2; ++ct) {
                        short8 bh8 = *(const short8*)&vh[(ct * 16 + ln) * 168 + lb];
                        short8 bl8 = *(const short8*)&vl[(ct * 16 + ln) * 168 + lb];
                        acc[r][ct] = __builtin_amdgcn_mfma_f32_16x16x32_bf16(ah, bh8, acc[r][ct], 0, 0, 0);
                        acc[r][ct] = __builtin_amdgcn_mfma_f32_16x16x32_bf16(ah, bl8, acc[r][ct], 0, 0, 0);
                        acc[r][ct] = __builtin_amdgcn_mfma_f32_16x16x32_bf16(al, bh8, acc[r][ct], 0, 0, 0);
                    }
                }
            }
        }
        // store: D row = rt*16 + quad*4 + rr, col = ct*16 + ln
#pragma unroll
        for (int r = 0; r < 3; ++r) {
            int rt = wave + 8 * r;
            if (rt >= 19) continue;
#pragma unroll
            for (int ct = 0; ct < 2; ++ct) {
#pragma unroll
                for (int rr = 0; rr < 4; ++rr) {
                    int p = rt * 16 + quad * 4 + rr;
                    if (p > 288) continue;
                    float v = acc[r][ct][rr];
                    ushort_t hh = f2bf(v);
                    size_t off = (rowbase + p) * 768 + h * 32 + ct * 16 + ln;
                    yhi[off] = hh;
                    ylo[off] = f2bf(v - bf2f(hh));
                }
            }
        }
    }

    // ---- P4: x_vs (aS2 = normalize(aS*ebS)) -> y cols 256..511 ----------
    for (int ch = 0; ch < 2; ++ch) {
        __syncthreads();
        for (int idx = t; idx < 1156; idx += 512) {
            int p = idx >> 2, c = idx & 3;
            *(float4*)&buf[p * 20 + c * 4] =
                *(const float4*)&qkv5[(rowbase + p) * 1280 + 512 + h * 32 + ch * 16 + c * 4];
        }
        __syncthreads();
        for (int u = t; u < 1156; u += 512) {
            const int c4 = (u & 3) * 4, rest = u >> 2;   // rest 0..288
            const int n = rest % 17, j = rest / 17;
            const float* as = &aS[n * 289 + j * 17];
            const float* eb = &ebS[j * 17];
            float s = 0.f;
#pragma unroll
            for (int kk = 0; kk < 17; ++kk) s += as[kk] * eb[kk];
            const float inv = 1.f / s;
            float4 a0 = {0,0,0,0};
            for (int kk = 0; kk < 17; ++kk) {
                float4 v = *(const float4*)&buf[(kk * 17 + n) * 20 + c4];
                fma4(a0, as[kk] * eb[kk], v);
            }
            a0.x *= inv; a0.y *= inv; a0.z *= inv; a0.w *= inv;
            store_hilo(yhi, ylo, (rowbase + j * 17 + n) * 768 + 256 + h * 32 + ch * 16 + c4, a0);
        }
    }

    // ---- P5: x_vv (aV2 = normalize(aV*ebV)) -> y cols 512..767 ----------
    for (int ch = 0; ch < 2; ++ch) {
        __syncthreads();
        for (int idx = t; idx < 1156; idx += 512) {
            int p = idx >> 2, c = idx & 3;
            *(float4*)&buf[p * 20 + c * 4] =
                *(const float4*)&qkv5[(rowbase + p) * 1280 + 768 + h * 32 + ch * 16 + c * 4];
        }
        __syncthreads();
        for (int u = t; u < 1156; u += 512) {
            const int c4 = (u & 3) * 4, rest = u >> 2;   // rest 0..288
            const int j = rest % 17, n = rest / 17;
            const float* av = &aV[j * 289 + n * 17];
            const float* eb = &ebV[n * 17];
            float s = 0.f;
#pragma unroll
            for (int mm = 0; mm < 17; ++mm) s += av[mm] * eb[mm];
            const float inv = 1.f / s;
            float4 a0 = {0,0,0,0};
            for (int mm = 0; mm < 17; ++mm) {
                float4 v = *(const float4*)&buf[(j * 17 + mm) * 20 + c4];
                fma4(a0, av[mm] * eb[mm], v);
            }
            a0.x *= inv; a0.y *= inv; a0.z *= inv; a0.w *= inv;
            store_hilo(yhi, ylo, (rowbase + j * 17 + n) * 768 + 512 + h * 32 + ch * 16 + c4, a0);
        }
    }
}

extern "C" void kernel_launch(void* const* d_in, const int* in_sizes, int n_in,
                              void* d_out, int out_size, void* d_ws, size_t ws_size,
                              hipStream_t stream)
{
    const float* x    = (const float*)d_in[0];
    const float* A_s  = (const float*)d_in[1];
    const float* A_v  = (const float*)d_in[2];
    const float* Wqkv = (const float*)d_in[3];
    const float* Wp   = (const float*)d_in[4];
    const float* bp   = (const float*)d_in[5];
    const float* M    = (const float*)d_in[6];
    const float* adjS = (const float*)d_in[7];
    const float* adjV = (const float*)d_in[8];
    float* out = (float*)d_out;

    char* w = (char*)d_ws;
    float*    qkv5  = (float*)w;                          // 94.7 MB, dead after k_att
    ushort_t* wph   = (ushort_t*)(w + 94699520);          // dead gap after qkv5
    ushort_t* wpl   = (ushort_t*)(w + 94699520 + 393216);
    char* R = w + 134946816;
    ushort_t* xhi = (ushort_t*)R;
    ushort_t* xlo = (ushort_t*)(R + 9469952);
    ushort_t* wqh = (ushort_t*)(R + 18939904);
    ushort_t* wql = (ushort_t*)(R + 19595264);
    ushort_t* yhi = (ushort_t*)R;                         // alias (after qkv gemm done)
    ushort_t* ylo = (ushort_t*)(R + 28422144);

    k_cvt_xw<<<dim3(6160), 256, 0, stream>>>((const float4*)x, (ushort4*)xhi, (ushort4*)xlo,
                                             Wqkv, wqh, wql, Wp, wph, wpl);
    k_gemm<128, 128, 256, 0><<<dim3(10, 145), 256, 0, stream>>>(xhi, xlo, wqh, wql, M, qkv5);
    k_att<<<dim3(512), 512, 0, stream>>>(qkv5, A_s, A_v, adjS, adjV, yhi, ylo);
    k_gemm<128, 64, 768, 1><<<dim3(4, 145), 256, 0, stream>>>(yhi, ylo, wph, wpl, bp, out);
}

// Round 9
// 254.427 us; speedup vs baseline: 1.2171x; 1.0026x over previous
//
#include <hip/hip_runtime.h>
#include <math.h>

#define ROWS 18496          // bt*J*N = 64*17*17
#define SCALE 0.17677669529663687f  // 1/sqrt(32)

typedef unsigned short ushort_t;
typedef __attribute__((ext_vector_type(8))) short short8;
typedef __attribute__((ext_vector_type(4))) float f32x4;

__device__ __forceinline__ void fma4(float4& d, float s, const float4& v) {
    d.x = fmaf(s, v.x, d.x); d.y = fmaf(s, v.y, d.y);
    d.z = fmaf(s, v.z, d.z); d.w = fmaf(s, v.w, d.w);
}
__device__ __forceinline__ float dot4(const float4& a, const float4& b) {
    return a.x*b.x + a.y*b.y + a.z*b.z + a.w*b.w;
}

__device__ __forceinline__ ushort_t f2bf(float x) {
    union { float f; unsigned u; } v; v.f = x;
    unsigned r = v.u + 0x7fffu + ((v.u >> 16) & 1u);
    return (ushort_t)(r >> 16);
}
__device__ __forceinline__ float bf2f(ushort_t b) {
    union { unsigned u; float f; } v; v.u = ((unsigned)b) << 16; return v.f;
}

// packed f32-pair -> 2xbf16 (1 instr). Splits using it are self-correcting:
// lo = v - asfloat(hi) is computed from the ACTUAL hi, so hi+lo == v to f32
// precision regardless of the cvt rounding mode.
__device__ __forceinline__ unsigned cvtpk(float a, float b) {
    unsigned r;
    asm("v_cvt_pk_bf16_f32 %0, %1, %2" : "=v"(r) : "v"(a), "v"(b));
    return r;
}
__device__ __forceinline__ float uasf(unsigned u) {
    union { unsigned u; float f; } v; v.u = u; return v.f;
}

__device__ __forceinline__ void gl_lds16(const void* g, void* l) {
    __builtin_amdgcn_global_load_lds(
        (const __attribute__((address_space(1))) void*)g,
        (__attribute__((address_space(3))) void*)l, 16, 0, 0);
}

__device__ __forceinline__ void store_hilo(ushort_t* yhi, ushort_t* ylo,
                                           size_t off, const float4& a)
{
    unsigned h01 = cvtpk(a.x, a.y), h23 = cvtpk(a.z, a.w);
    unsigned l01 = cvtpk(a.x - uasf(h01 << 16), a.y - uasf(h01 & 0xffff0000u));
    unsigned l23 = cvtpk(a.z - uasf(h23 << 16), a.w - uasf(h23 & 0xffff0000u));
    *(uint2*)&yhi[off] = (uint2){h01, h23};
    *(uint2*)&ylo[off] = (uint2){l01, l23};
}

// ---------------- merged conversion kernel (x, Wqkv, Wp) ---------------
__global__ __launch_bounds__(256) void k_cvt_xw(
    const float4* __restrict__ x, ushort4* __restrict__ xhi, ushort4* __restrict__ xlo,
    const float* __restrict__ W, ushort_t* __restrict__ bh, ushort_t* __restrict__ bl,
    const float* __restrict__ Wp, ushort_t* __restrict__ wph, ushort_t* __restrict__ wpl)
{
    if (blockIdx.x < 4624) {
        int i = blockIdx.x * 256 + threadIdx.x;
        float4 v = x[i];
        ushort4 h, l;
        h.x = f2bf(v.x); l.x = f2bf(v.x - bf2f(h.x));
        h.y = f2bf(v.y); l.y = f2bf(v.y - bf2f(h.y));
        h.z = f2bf(v.z); l.z = f2bf(v.z - bf2f(h.z));
        h.w = f2bf(v.w); l.w = f2bf(v.w - bf2f(h.w));
        xhi[i] = h; xlo[i] = l;
    } else if (blockIdx.x < 5904) {
        int o = blockIdx.x - 4624;   // 0..1279
        int kk = threadIdx.x;        // 0..255
        int col = (o & 255) * 5 + (o >> 8);
        float v = W[(size_t)kk * 1280 + col];
        ushort_t hh = f2bf(v);
        bh[(size_t)o * 256 + kk] = hh;
        bl[(size_t)o * 256 + kk] = f2bf(v - bf2f(hh));
    } else {
        // Wp (768x256 f32) -> transposed bf16 [n][k]
        int n = blockIdx.x - 5904;   // 0..255
        for (int k = threadIdx.x; k < 768; k += 256) {
            float v = Wp[(size_t)k * 256 + n];
            ushort_t h = f2bf(v);
            wph[(size_t)n * 768 + k] = h;
            wpl[(size_t)n * 768 + k] = f2bf(v - bf2f(h));
        }
    }
}

// ---------------- split-bf16 MFMA GEMM --------------------------------
// XCD-aware bijective block remap (T1 + m204 bijective form): round-8
// measured -18 us total on the two GEMMs.
template<int BM, int BN, int K, int MODE>
__global__ __launch_bounds__(256) void k_gemm(
    const ushort_t* __restrict__ Ahi, const ushort_t* __restrict__ Alo,
    const ushort_t* __restrict__ Bhi, const ushort_t* __restrict__ Blo,
    const float* __restrict__ aux,
    float* __restrict__ out)
{
    constexpr int MT = BM / 32;
    constexpr int NT = BN / 32;
    __shared__ __attribute__((aligned(16))) ushort_t sAh[BM * 32];
    __shared__ __attribute__((aligned(16))) ushort_t sAl[BM * 32];
    __shared__ __attribute__((aligned(16))) ushort_t sBh[BN * 32];
    __shared__ __attribute__((aligned(16))) ushort_t sBl[BN * 32];

    const int t = threadIdx.x;
    const int lane = t & 63;
    const int ln = lane & 15, quad = lane >> 4;
    const int wave = t >> 6;
    const int wm = wave >> 1, wn = wave & 1;

    const int nwg = (int)(gridDim.x * gridDim.y);
    int wgid = (int)(blockIdx.y * gridDim.x + blockIdx.x);
    int q = nwg >> 3, r = nwg & 7;
    int xcd = wgid & 7, i0 = wgid >> 3;
    int base = (xcd < r) ? xcd * (q + 1) : r * (q + 1) + (xcd - r) * q;
    int logical = base + i0;
    const int m0 = (logical / (int)gridDim.x) * BM;
    const int n0 = (logical % (int)gridDim.x) * BN;

    f32x4 acc[MT][NT];
#pragma unroll
    for (int i = 0; i < MT; ++i)
#pragma unroll
        for (int j = 0; j < NT; ++j) acc[i][j] = (f32x4){0.f, 0.f, 0.f, 0.f};

    for (int kb = 0; kb < K; kb += 32) {
        __syncthreads();
#pragma unroll
        for (int s = t; s < BM * 4; s += 256) {
            int row = s >> 2, kc = s & 3;
            int gr = m0 + row; if (gr > ROWS - 1) gr = ROWS - 1;
            size_t gb = ((size_t)gr * K + kb) * 2 + kc * 16;
            int lb = (s & ~63) * 16;
            gl_lds16((const char*)Ahi + gb, (char*)sAh + lb);
            gl_lds16((const char*)Alo + gb, (char*)sAl + lb);
        }
#pragma unroll
        for (int s = t; s < BN * 4; s += 256) {
            int row = s >> 2, kc = s & 3;
            size_t gb = ((size_t)(n0 + row) * K + kb) * 2 + kc * 16;
            int lb = (s & ~63) * 16;
            gl_lds16((const char*)Bhi + gb, (char*)sBh + lb);
            gl_lds16((const char*)Blo + gb, (char*)sBl + lb);
        }
        __syncthreads();

        short8 ah[MT], al[MT], bh[NT], bl[NT];
#pragma unroll
        for (int i = 0; i < MT; ++i) {
            int off = (wm * (BM / 2) + i * 16 + ln) * 32 + quad * 8;
            ah[i] = *(const short8*)&sAh[off];
            al[i] = *(const short8*)&sAl[off];
        }
#pragma unroll
        for (int j = 0; j < NT; ++j) {
            int off = (wn * (BN / 2) + j * 16 + ln) * 32 + quad * 8;
            bh[j] = *(const short8*)&sBh[off];
            bl[j] = *(const short8*)&sBl[off];
        }
#pragma unroll
        for (int i = 0; i < MT; ++i)
#pragma unroll
            for (int j = 0; j < NT; ++j) {
                acc[i][j] = __builtin_amdgcn_mfma_f32_16x16x32_bf16(ah[i], bh[j], acc[i][j], 0, 0, 0);
                acc[i][j] = __builtin_amdgcn_mfma_f32_16x16x32_bf16(ah[i], bl[j], acc[i][j], 0, 0, 0);
                acc[i][j] = __builtin_amdgcn_mfma_f32_16x16x32_bf16(al[i], bh[j], acc[i][j], 0, 0, 0);
            }
    }

#pragma unroll
    for (int i = 0; i < MT; ++i) {
#pragma unroll
        for (int r2 = 0; r2 < 4; ++r2) {
            int gm = m0 + wm * (BM / 2) + i * 16 + quad * 4 + r2;
            if (gm >= ROWS) continue;
            if (MODE == 0) {
                int jn = gm % 289;
                const float* Mrow = &aux[(size_t)jn * 256];
#pragma unroll
                for (int j = 0; j < NT; ++j) {
                    int gn = n0 + wn * (BN / 2) + j * 16 + ln;
                    out[(size_t)gm * 1280 + gn] = acc[i][j][r2] * Mrow[gn & 255];
                }
            } else {
#pragma unroll
                for (int j = 0; j < NT; ++j) {
                    int gn = n0 + wn * (BN / 2) + j * 16 + ln;
                    out[(size_t)gm * 256 + gn] = acc[i][j][r2] + aux[gn];
                }
            }
        }
    }
}

// ---------------- fused attention: scores + softmaxes + all combines -----
// 512 threads (8 waves) per (b,h), grid 512. LDS 63.5 KB, (512,4) = 64 VGPR
// cap -> 2 blocks/CU. Round-9: VALU diet via v_cvt_pk_bf16_f32 — all bf16
// hi/lo splits (P3 A-build, P3 staging/epilogue, store_hilo) use the packed
// 1-instr convert instead of the 3-op integer emulation; P3 A-build also
// hoists the aS read across each <=1-wrap (k17,m17) run.
__global__ __launch_bounds__(512, 4) void k_att(
    const float* __restrict__ qkv5,
    const float* __restrict__ A_s, const float* __restrict__ A_v,
    const float* __restrict__ adjS, const float* __restrict__ adjV,
    ushort_t* __restrict__ yhi, ushort_t* __restrict__ ylo)
{
    __shared__ __attribute__((aligned(16))) float sm[16184];
    float* aS  = sm;            // 4913  [n][j][k]
    float* aV  = sm + 4913;     // 4913  [j][n][m]
    float* ebS = sm + 9826;     // 289
    float* ebV = sm + 10115;    // 289
    float* buf = sm + 10404;    // 289*20 f32 (P1/P4/P5)  |  P3: vsv_t hi/lo

    const int t  = threadIdx.x;
    const int bh = blockIdx.x;
    const int b  = bh >> 3, h = bh & 7;
    const size_t rowbase = (size_t)b * 289;

    // ---- P0: exp of symmetrized biases ----
    for (int idx = t; idx < 578; idx += 512) {
        int f = idx / 289, rem = idx % 289;
        int jj = rem / 17, kk = rem % 17;
        float bias;
        if (f == 0)
            bias = 0.5f * ((A_s[jj*17+kk] + adjS[jj*17+kk]) + (A_s[kk*17+jj] + adjS[kk*17+jj]));
        else
            bias = 0.5f * ((A_v[jj*17+kk] + adjV[jj*17+kk]) + (A_v[kk*17+jj] + adjV[kk*17+jj]));
        (f ? ebV : ebS)[rem] = expf(bias);
    }

    // ---- P1: raw scores, accumulated directly in LDS (no reg arrays) ----
    for (int ch = 0; ch < 2; ++ch) {
        __syncthreads();
        for (int idx = t; idx < 1156; idx += 512) {
            int p = idx >> 2, c = idx & 3;
            *(float4*)&buf[p * 20 + c * 4] =
                *(const float4*)&qkv5[(rowbase + p) * 1280 + 256 + h * 32 + ch * 16 + c * 4];
        }
        __syncthreads();
        for (int u = t; u < 578; u += 512) {
            const bool isS = (u < 289);
            const int p = isS ? u : u - 289;
            const float* qp = &qkv5[(rowbase + p) * 1280 + h * 32 + ch * 16];
            float4 q0 = *(const float4*)&qp[0];
            float4 q1 = *(const float4*)&qp[4];
            float4 q2 = *(const float4*)&qp[8];
            float4 q3 = *(const float4*)&qp[12];
            const int a = p / 17, bb = p % 17;
            if (isS) {
                float* dst = &aS[bb * 289 + a * 17];
#pragma unroll
                for (int kk = 0; kk < 17; ++kk) {
                    const float4* r = (const float4*)&buf[(kk * 17 + bb) * 20];
                    float val = dot4(q0, r[0]) + dot4(q1, r[1]) + dot4(q2, r[2]) + dot4(q3, r[3]);
                    if (ch == 0) dst[kk] = val; else dst[kk] += val;
                }
            } else {
                float* dst = &aV[a * 289 + bb * 17];
#pragma unroll
                for (int mm = 0; mm < 17; ++mm) {
                    const float4* r = (const float4*)&buf[(a * 17 + mm) * 20];
                    float val = dot4(q0, r[0]) + dot4(q1, r[1]) + dot4(q2, r[2]) + dot4(q3, r[3]);
                    if (ch == 0) dst[mm] = val; else dst[mm] += val;
                }
            }
        }
    }
    __syncthreads();

    // ---- P2: in-place 3-pass softmax on all 578 rows (SCALE folded) ----
    for (int idx = t; idx < 578; idx += 512) {
        float* row = (idx < 289) ? &aS[idx * 17] : &aV[(idx - 289) * 17];
        float mx = row[0];
#pragma unroll
        for (int kk = 1; kk < 17; ++kk) mx = fmaxf(mx, row[kk]);
        float sum = 0.f;
#pragma unroll
        for (int kk = 0; kk < 17; ++kk) {
            float e = expf((row[kk] - mx) * SCALE);
            row[kk] = e; sum += e;
        }
        float inv = 1.f / sum;
#pragma unroll
        for (int kk = 0; kk < 17; ++kk) row[kk] *= inv;
    }
    // (no trailing sync: P3's staging sync orders P2 before consumers)

    // ---- P3: x_vsv via in-register-A split-bf16 MFMA ----
    {
        const int lane = t & 63;
        const int ln = lane & 15, quad = lane >> 4;
        const int wave = t >> 6;                  // 0..7
        ushort_t* vh = (ushort_t*)buf;            // [32][168] bf16 hi (pad 168)
        ushort_t* vl = vh + 32 * 168;             // lo

        f32x4 acc[3][2];
#pragma unroll
        for (int r = 0; r < 3; ++r) {
            acc[r][0] = (f32x4){0.f,0.f,0.f,0.f};
            acc[r][1] = (f32x4){0.f,0.f,0.f,0.f};
        }

        // per-lane row bases for the (up to) 3 row-tiles this wave owns
        int sbase[3], vbase[3];
#pragma unroll
        for (int r = 0; r < 3; ++r) {
            int p = (wave + 8 * r) * 16 + ln; if (p > 288) p = 288;
            int jj = (p * 61681) >> 20;           // p / 17
            int nn = p - jj * 17;
            sbase[r] = nn * 289 + jj * 17;        // aS row (n,j)
            vbase[r] = jj * 289 + nn * 17;        // aV row (j,n)
        }

        for (int khalf = 0; khalf < 2; ++khalf) {
            const int qbase = khalf * 160;
            const int V = khalf ? 129 : 160;      // valid q's this half
            __syncthreads();
            if (khalf == 1) {
                // bulk zero vh+vl (cols >=129 must be 0; reads reach col 159)
                uint4* z = (uint4*)vh;            // vh,vl contiguous: 1344 uint4
                for (int e = t; e < 1344; e += 512) z[e] = (uint4){0,0,0,0};
                __syncthreads();
            }
            // stage vsv transposed: vh/vl[c][ql], coalesced global reads
            for (int e = t; e < 32 * V; e += 512) {
                int ql = e >> 5, c = e & 31;
                float v = qkv5[(rowbase + qbase + ql) * 1280 + 1024 + h * 32 + c];
                unsigned hp = cvtpk(v, v);
                float lo = v - uasf(hp << 16);
                unsigned lp = cvtpk(lo, lo);
                vh[c * 168 + ql] = (ushort_t)hp;
                vl[c * 168 + ql] = (ushort_t)lp;
            }
            __syncthreads();
#pragma unroll
            for (int kstep = 0; kstep < 5; ++kstep) {
                const int q0 = qbase + kstep * 32 + quad * 8;
                const int lb = kstep * 32 + quad * 8;
#pragma unroll
                for (int r = 0; r < 3; ++r) {
                    if (r == 2 && wave >= 3) continue;   // rt>=19: no output
                    union { short8 s; unsigned u[4]; } A, L;
                    int qc0 = (q0 < 289) ? q0 : 288;     // clamp: in-bounds decode
                    int k17 = (qc0 * 61681) >> 20;       // qc0 / 17
                    int m17 = qc0 - k17 * 17;
                    float sv = aS[sbase[r] + k17];
#pragma unroll
                    for (int i2 = 0; i2 < 4; ++i2) {
                        float pv0 = sv * aV[vbase[r] + m17];
                        ++m17; if (m17 == 17) { m17 = 0; ++k17; sv = aS[sbase[r] + k17]; }
                        float pv1 = sv * aV[vbase[r] + m17];
                        ++m17; if (m17 == 17) { m17 = 0; ++k17; sv = aS[sbase[r] + k17]; }
                        if (khalf == 1) {                // khalf0: q <= 159 always valid
                            if (q0 + 2 * i2     >= 289) pv0 = 0.f;
                            if (q0 + 2 * i2 + 1 >= 289) pv1 = 0.f;
                        }
                        unsigned hp = cvtpk(pv0, pv1);
                        unsigned lp = cvtpk(pv0 - uasf(hp << 16),
                                            pv1 - uasf(hp & 0xffff0000u));
                        A.u[i2] = hp; L.u[i2] = lp;
                    }
#pragma unroll
                    for (int ct = 0; ct < 2; ++ct) {
                        short8 bh8 = *(const short8*)&vh[(ct * 16 + ln) * 168 + lb];
                        short8 bl8 = *(const short8*)&vl[(ct * 16 + ln) * 168 + lb];
                        acc[r][ct] = __builtin_amdgcn_mfma_f32_16x16x32_bf16(A.s, bh8, acc[r][ct], 0, 0, 0);
                        acc[r][ct] = __builtin_amdgcn_mfma_f32_16x16x32_bf16(A.s, bl8, acc[r][ct], 0, 0, 0);
                        acc[r][ct] = __builtin_amdgcn_mfma_f32_16x16x32_bf16(L.s, bh8, acc[r][ct], 0, 0, 0);
                    }
                }
            }
        }
        // store: D row = rt*16 + quad*4 + rr, col = ct*16 + ln
#pragma unroll
        for (int r = 0; r < 3; ++r) {
            int rt = wave + 8 * r;
            if (rt >= 19) continue;
#pragma unroll
            for (int ct = 0; ct < 2; ++ct) {
#pragma unroll
                for (int rr = 0; rr < 4; ++rr) {
                    int p = rt * 16 + quad * 4 + rr;
                    if (p > 288) continue;
                    float v = acc[r][ct][rr];
                    unsigned hp = cvtpk(v, v);
                    float lo = v - uasf(hp << 16);
                    unsigned lp = cvtpk(lo, lo);
                    size_t off = (rowbase + p) * 768 + h * 32 + ct * 16 + ln;
                    yhi[off] = (ushort_t)hp;
                    ylo[off] = (ushort_t)lp;
                }
            }
        }
    }

    // ---- P4: x_vs (aS2 = normalize(aS*ebS)) -> y cols 256..511 ----------
    for (int ch = 0; ch < 2; ++ch) {
        __syncthreads();
        for (int idx = t; idx < 1156; idx += 512) {
            int p = idx >> 2, c = idx & 3;
            *(float4*)&buf[p * 20 + c * 4] =
                *(const float4*)&qkv5[(rowbase + p) * 1280 + 512 + h * 32 + ch * 16 + c * 4];
        }
        __syncthreads();
        for (int u = t; u < 1156; u += 512) {
            const int c4 = (u & 3) * 4, rest = u >> 2;   // rest 0..288
            const int n = rest % 17, j = rest / 17;
            const float* as = &aS[n * 289 + j * 17];
            const float* eb = &ebS[j * 17];
            float s = 0.f;
#pragma unroll
            for (int kk = 0; kk < 17; ++kk) s += as[kk] * eb[kk];
            const float inv = 1.f / s;
            float4 a0 = {0,0,0,0};
            for (int kk = 0; kk < 17; ++kk) {
                float4 v = *(const float4*)&buf[(kk * 17 + n) * 20 + c4];
                fma4(a0, as[kk] * eb[kk], v);
            }
            a0.x *= inv; a0.y *= inv; a0.z *= inv; a0.w *= inv;
            store_hilo(yhi, ylo, (rowbase + j * 17 + n) * 768 + 256 + h * 32 + ch * 16 + c4, a0);
        }
    }

    // ---- P5: x_vv (aV2 = normalize(aV*ebV)) -> y cols 512..767 ----------
    for (int ch = 0; ch < 2; ++ch) {
        __syncthreads();
        for (int idx = t; idx < 1156; idx += 512) {
            int p = idx >> 2, c = idx & 3;
            *(float4*)&buf[p * 20 + c * 4] =
                *(const float4*)&qkv5[(rowbase + p) * 1280 + 768 + h * 32 + ch * 16 + c * 4];
        }
        __syncthreads();
        for (int u = t; u < 1156; u += 512) {
            const int c4 = (u & 3) * 4, rest = u >> 2;   // rest 0..288
            const int j = rest % 17, n = rest / 17;
            const float* av = &aV[j * 289 + n * 17];
            const float* eb = &ebV[n * 17];
            float s = 0.f;
#pragma unroll
            for (int mm = 0; mm < 17; ++mm) s += av[mm] * eb[mm];
            const float inv = 1.f / s;
            float4 a0 = {0,0,0,0};
            for (int mm = 0; mm < 17; ++mm) {
                float4 v = *(const float4*)&buf[(j * 17 + mm) * 20 + c4];
                fma4(a0, av[mm] * eb[mm], v);
            }
            a0.x *= inv; a0.y *= inv; a0.z *= inv; a0.w *= inv;
            store_hilo(yhi, ylo, (rowbase + j * 17 + n) * 768 + 512 + h * 32 + ch * 16 + c4, a0);
        }
    }
}

extern "C" void kernel_launch(void* const* d_in, const int* in_sizes, int n_in,
                              void* d_out, int out_size, void* d_ws, size_t ws_size,
                              hipStream_t stream)
{
    const float* x    = (const float*)d_in[0];
    const float* A_s  = (const float*)d_in[1];
    const float* A_v  = (const float*)d_in[2];
    const float* Wqkv = (const float*)d_in[3];
    const float* Wp   = (const float*)d_in[4];
    const float* bp   = (const float*)d_in[5];
    const float* M    = (const float*)d_in[6];
    const float* adjS = (const float*)d_in[7];
    const float* adjV = (const float*)d_in[8];
    float* out = (float*)d_out;

    char* w = (char*)d_ws;
    float*    qkv5  = (float*)w;                          // 94.7 MB, dead after k_att
    ushort_t* wph   = (ushort_t*)(w + 94699520);          // dead gap after qkv5
    ushort_t* wpl   = (ushort_t*)(w + 94699520 + 393216);
    char* R = w + 134946816;
    ushort_t* xhi = (ushort_t*)R;
    ushort_t* xlo = (ushort_t*)(R + 9469952);
    ushort_t* wqh = (ushort_t*)(R + 18939904);
    ushort_t* wql = (ushort_t*)(R + 19595264);
    ushort_t* yhi = (ushort_t*)R;                         // alias (after qkv gemm done)
    ushort_t* ylo = (ushort_t*)(R + 28422144);

    k_cvt_xw<<<dim3(6160), 256, 0, stream>>>((const float4*)x, (ushort4*)xhi, (ushort4*)xlo,
                                             Wqkv, wqh, wql, Wp, wph, wpl);
    k_gemm<128, 128, 256, 0><<<dim3(10, 145), 256, 0, stream>>>(xhi, xlo, wqh, wql, M, qkv5);
    k_att<<<dim3(512), 512, 0, stream>>>(qkv5, A_s, A_v, adjS, adjV, yhi, ylo);
    k_gemm<128, 64, 768, 1><<<dim3(4, 145), 256, 0, stream>>>(yhi, ylo, wph, wpl, bp, out);
}